// Round 15
// baseline (682.028 us; speedup 1.0000x reference)
//
#include <hip/hip_runtime.h>

#define N_NODES 50000
#define N_EDGES 640000
#define HID 128
#define EDGE_DIM 32
#define NUM_GRAPHS 512
#define BN_EPS 1e-5f
#define NGRP16 3125    // N_NODES / 16 (exact)
#define NGB4 12500     // N_NODES / 4 (exact) — gather blocks
#define NSCB 49        // ceil(N_NODES/1024)

typedef unsigned int uint32;
typedef unsigned long long uint64;
typedef unsigned short ushort;
typedef __attribute__((ext_vector_type(8))) short short8;   // 8 bf16 (4 VGPR)
typedef __attribute__((ext_vector_type(4))) float f32x4;    // MFMA accum

// round-to-nearest-even f32 -> bf16 bits
__device__ inline ushort f2bf(float x) {
    uint32 u = __float_as_uint(x);
    return (ushort)((u + 0x7fff + ((u >> 16) & 1)) >> 16);
}

// ---------------------------------------------------------------------------
// Merged preprocessing: blocks [0,2500) histogram deg; blocks [2500,2530)
// pack the 3 layers' weights into MFMA fragment layout.
// ---------------------------------------------------------------------------
__global__ __launch_bounds__(256) void pre_kernel(
        const int* __restrict__ eidx, int* __restrict__ deg,
        const float* __restrict__ Wn0, const float* __restrict__ We0,
        const float* __restrict__ Wn1, const float* __restrict__ We1,
        const float* __restrict__ Wn2, const float* __restrict__ We2,
        short8* __restrict__ Wnp0, short8* __restrict__ Wep0,
        short8* __restrict__ Wnp1, short8* __restrict__ Wep1,
        short8* __restrict__ Wnp2, short8* __restrict__ Wep2) {
    int b = blockIdx.x;
    if (b < 2500) {
        int e = b * 256 + threadIdx.x;          // N_EDGES = 2500*256 exactly
        atomicAdd(&deg[eidx[N_EDGES + e]], 1);
        return;
    }
    int idx = b - 2500;                          // 0..29
    int layer = idx / 10;
    int t = (idx % 10) * 256 + threadIdx.x;      // 0..2559
    const float* Wn = (layer == 0) ? Wn0 : (layer == 1) ? Wn1 : Wn2;
    const float* We = (layer == 0) ? We0 : (layer == 1) ? We1 : We2;
    short8* Wnp = (layer == 0) ? Wnp0 : (layer == 1) ? Wnp1 : Wnp2;
    short8* Wep = (layer == 0) ? Wep0 : (layer == 1) ? Wep1 : Wep2;
    if (t < 2048) {
        int l = t & 63, rest = t >> 6;
        int kb = rest & 3, nt = rest >> 2;
        int col = nt * 16 + (l & 15);
        int k0 = kb * 32 + (l >> 4) * 8;
        short8 v;
        #pragma unroll
        for (int j = 0; j < 8; ++j) v[j] = (short)f2bf(Wn[(k0 + j) * 128 + col]);
        Wnp[t] = v;
    } else if (t < 2560) {
        int e = t - 2048;
        int l = e & 63, nt = e >> 6;
        int col = nt * 16 + (l & 15);
        int k0 = (l >> 4) * 8;
        short8 v;
        #pragma unroll
        for (int j = 0; j < 8; ++j) v[j] = (short)f2bf(We[(k0 + j) * 128 + col]);
        Wep[e] = v;
    }
}

// ---------------------------------------------------------------------------
// One-dispatch exclusive scan: each block redundantly sums deg[0 .. b*1024)
// ---------------------------------------------------------------------------
__global__ __launch_bounds__(256) void scan_kernel(const int* __restrict__ deg,
                                                   int* __restrict__ rowp) {
    __shared__ int red[256];
    int b = blockIdx.x, tid = threadIdx.x;
    int pre = 0;
    int limit = b * 1024;
    for (int i = tid; i < limit; i += 256) pre += deg[i];
    red[tid] = pre;
    __syncthreads();
    for (int off = 128; off > 0; off >>= 1) {
        if (tid < off) red[tid] += red[tid + off];
        __syncthreads();
    }
    int base = red[0];
    __syncthreads();
    int basei = b * 1024 + tid * 4;
    int v[4];
    int s = 0;
    #pragma unroll
    for (int j = 0; j < 4; ++j) {
        int i = basei + j;
        v[j] = (i < N_NODES) ? deg[i] : 0;
        s += v[j];
    }
    red[tid] = s;
    __syncthreads();
    for (int off = 1; off < 256; off <<= 1) {
        int t = (tid >= off) ? red[tid - off] : 0;
        __syncthreads();
        red[tid] += t;
        __syncthreads();
    }
    int excl = base + red[tid] - s;
    #pragma unroll
    for (int j = 0; j < 4; ++j) {
        int i = basei + j;
        if (i < N_NODES) rowp[i] = excl;
        excl += v[j];
    }
    if (b == 0 && tid == 0) rowp[N_NODES] = N_EDGES;
}

// ---------------------------------------------------------------------------
// CSR fill (packed): csr_pk[p] = (eid << 32) | src — one 8B scatter per edge
// ---------------------------------------------------------------------------
__global__ void fill_csr_kernel(const int* __restrict__ eidx,
                                const int* __restrict__ rowp,
                                int* __restrict__ cursor,
                                uint64* __restrict__ csr_pk) {
    int e = blockIdx.x * 256 + threadIdx.x;
    if (e >= N_EDGES) return;
    int d = eidx[N_EDGES + e];
    int pos = rowp[d] + atomicAdd(&cursor[d], 1);
    csr_pk[pos] = ((uint64)(uint32)e << 32) | (uint32)eidx[e];
}

// ---------------------------------------------------------------------------
// Eab[d] = bf16( sum of edge_attr rows with dst == d )   (GEMM A-operand)
// ---------------------------------------------------------------------------
__global__ __launch_bounds__(256) void ea_gather_kernel(
        const float* __restrict__ edge_attr,
        const int* __restrict__ rowp,
        const uint64* __restrict__ csr_pk,
        ushort* __restrict__ Eab) {
    int node = blockIdx.x * 8 + (threadIdx.x >> 5);
    int c = threadIdx.x & 31;
    if (node >= N_NODES) return;
    int beg = rowp[node], end = rowp[node + 1];
    float s0 = 0.f, s1 = 0.f, s2 = 0.f, s3 = 0.f;
    int p = beg;
    for (; p + 4 <= end; p += 4) {
        int e0 = (int)(csr_pk[p]     >> 32);
        int e1 = (int)(csr_pk[p + 1] >> 32);
        int e2 = (int)(csr_pk[p + 2] >> 32);
        int e3 = (int)(csr_pk[p + 3] >> 32);
        s0 += edge_attr[e0 * EDGE_DIM + c];
        s1 += edge_attr[e1 * EDGE_DIM + c];
        s2 += edge_attr[e2 * EDGE_DIM + c];
        s3 += edge_attr[e3 * EDGE_DIM + c];
    }
    for (; p < end; ++p)
        s0 += edge_attr[(int)(csr_pk[p] >> 32) * EDGE_DIM + c];
    Eab[node * EDGE_DIM + c] = f2bf((s0 + s1) + (s2 + s3));
}

// ---------------------------------------------------------------------------
// MFMA GEMM with self-computed BN (scale/shift derived from csq in LDS).
// ---------------------------------------------------------------------------
template <bool BN>
__global__ __launch_bounds__(256) void gemm_mfma_kernel(
        const float* __restrict__ X, const short8* __restrict__ Wnp,
        const float* __restrict__ bnb,
        const ushort* __restrict__ eab, const short8* __restrict__ Wep,
        const float* __restrict__ be, const int* __restrict__ deg,
        const float* __restrict__ csq,
        const float* __restrict__ gamma, const float* __restrict__ beta,
        ushort* __restrict__ h16, float* __restrict__ acc) {
    __shared__ __align__(16) float scs[128];
    __shared__ __align__(16) float shs[128];
    const int tid = threadIdx.x;
    if (BN) {
        if (tid < 128) {
            const float invN = 1.0f / (float)N_NODES;
            float mu = csq[tid] * invN;
            float var = csq[128 + tid] * invN - mu * mu;
            float sc = gamma[tid] * rsqrtf(var + BN_EPS);
            scs[tid] = sc;
            shs[tid] = beta[tid] - mu * sc;
        }
        __syncthreads();
    }

    const int wid = tid >> 6, L = tid & 63;
    const int g = blockIdx.x * 4 + wid;
    if (g >= NGRP16) return;                    // wave-uniform exit (after barrier)
    const int r0 = g * 16;
    const int m = L & 15, kq = L >> 4;

    short8 afr[4];
    const float* xrow = X + (size_t)(r0 + m) * 128 + kq * 8;
    #pragma unroll
    for (int kb = 0; kb < 4; ++kb) {
        float v[8];
        *(float4*)&v[0] = *(const float4*)(xrow + kb * 32);
        *(float4*)&v[4] = *(const float4*)(xrow + kb * 32 + 4);
        if (BN) {
            float s[8], h[8];
            *(float4*)&s[0] = *(const float4*)(scs + kb * 32 + kq * 8);
            *(float4*)&s[4] = *(const float4*)(scs + kb * 32 + kq * 8 + 4);
            *(float4*)&h[0] = *(const float4*)(shs + kb * 32 + kq * 8);
            *(float4*)&h[4] = *(const float4*)(shs + kb * 32 + kq * 8 + 4);
            #pragma unroll
            for (int j = 0; j < 8; ++j)
                v[j] = fmaxf(0.f, v[j] * s[j] + h[j]);
        }
        short8 a;
        #pragma unroll
        for (int j = 0; j < 8; ++j) a[j] = (short)f2bf(v[j]);
        afr[kb] = a;
    }

    f32x4 d[8];
    #pragma unroll
    for (int nt = 0; nt < 8; ++nt) d[nt] = (f32x4)(0.f);

    #pragma unroll
    for (int kb = 0; kb < 4; ++kb) {
        #pragma unroll
        for (int nt = 0; nt < 8; ++nt) {
            short8 b = Wnp[(nt * 4 + kb) * 64 + L];
            d[nt] = __builtin_amdgcn_mfma_f32_16x16x32_bf16(afr[kb], b, d[nt], 0, 0, 0);
        }
    }

    float bnv[8], bev[8];
    #pragma unroll
    for (int nt = 0; nt < 8; ++nt) {
        bnv[nt] = bnb[nt * 16 + m];
        bev[nt] = be[nt * 16 + m];
    }

    #pragma unroll
    for (int nt = 0; nt < 8; ++nt) {
        #pragma unroll
        for (int i = 0; i < 4; ++i)
            h16[(size_t)(r0 + kq * 4 + i) * 128 + nt * 16 + m] =
                f2bf(d[nt][i] + bnv[nt]);
    }

    short8 ae = *(const short8*)(eab + (size_t)(r0 + m) * 32 + kq * 8);
    #pragma unroll
    for (int nt = 0; nt < 8; ++nt)
        d[nt] = __builtin_amdgcn_mfma_f32_16x16x32_bf16(ae, Wep[nt * 64 + L], d[nt], 0, 0, 0);

    float dg[4];
    #pragma unroll
    for (int i = 0; i < 4; ++i) dg[i] = (float)deg[r0 + kq * 4 + i];

    #pragma unroll
    for (int nt = 0; nt < 8; ++nt) {
        #pragma unroll
        for (int i = 0; i < 4; ++i)
            acc[(size_t)(r0 + kq * 4 + i) * 128 + nt * 16 + m] =
                d[nt][i] + bnv[nt] + dg[i] * bev[nt];
    }
}

// ---------------------------------------------------------------------------
// acc[d] += sum over CSR edges of h_bf16[src]  — fused column stats.
// ONE NODE PER WAVE (4 per block, grid 12500): full gather TLP (50000 waves,
// 8-deep MLP each) + end-of-block LDS stats reduce (fusion costs ~nothing).
// ---------------------------------------------------------------------------
__global__ __launch_bounds__(256) void gather_kernel(
        const uint32* __restrict__ h32,      // 64 uints (=128 bf16) per row
        const int* __restrict__ rowp, const uint64* __restrict__ csr_pk,
        float* __restrict__ acc, float* __restrict__ partial) {
    __shared__ float red_s[4][128];
    __shared__ float red_q[4][128];
    int wid = threadIdx.x >> 6, lane = threadIdx.x & 63;
    int node = blockIdx.x * 4 + wid;             // < N_NODES (12500*4 exact)
    int beg = rowp[node], end = rowp[node + 1];
    float sx[8] = {0.f,0.f,0.f,0.f,0.f,0.f,0.f,0.f};
    float sy[8] = {0.f,0.f,0.f,0.f,0.f,0.f,0.f,0.f};
    int p = beg;
    for (; p + 8 <= end; p += 8) {
        uint32 v[8];
        #pragma unroll
        for (int j = 0; j < 8; ++j)
            v[j] = h32[(int)(uint32)csr_pk[p + j] * 64 + lane];
        #pragma unroll
        for (int j = 0; j < 8; ++j) {
            sx[j] += __uint_as_float(v[j] << 16);
            sy[j] += __uint_as_float(v[j] & 0xffff0000u);
        }
    }
    for (; p + 4 <= end; p += 4) {
        uint32 v[4];
        #pragma unroll
        for (int j = 0; j < 4; ++j)
            v[j] = h32[(int)(uint32)csr_pk[p + j] * 64 + lane];
        #pragma unroll
        for (int j = 0; j < 4; ++j) {
            sx[j] += __uint_as_float(v[j] << 16);
            sy[j] += __uint_as_float(v[j] & 0xffff0000u);
        }
    }
    for (; p < end; ++p) {
        uint32 v = h32[(int)(uint32)csr_pk[p] * 64 + lane];
        sx[0] += __uint_as_float(v << 16);
        sy[0] += __uint_as_float(v & 0xffff0000u);
    }
    float2* ap = (float2*)&acc[(size_t)node * 128 + lane * 2];
    float2 a = *ap;
    a.x += ((sx[0] + sx[1]) + (sx[2] + sx[3])) + ((sx[4] + sx[5]) + (sx[6] + sx[7]));
    a.y += ((sy[0] + sy[1]) + (sy[2] + sy[3])) + ((sy[4] + sy[5]) + (sy[6] + sy[7]));
    *ap = a;
    red_s[wid][lane * 2]     = a.x;
    red_s[wid][lane * 2 + 1] = a.y;
    red_q[wid][lane * 2]     = a.x * a.x;
    red_q[wid][lane * 2 + 1] = a.y * a.y;
    __syncthreads();
    int t = threadIdx.x;
    if (t < 128) {
        float s = (red_s[0][t] + red_s[1][t]) + (red_s[2][t] + red_s[3][t]);
        partial[(size_t)blockIdx.x * 256 + t] = s;
    } else {
        int c = t - 128;
        float q = (red_q[0][c] + red_q[1][c]) + (red_q[2][c] + red_q[3][c]);
        partial[(size_t)blockIdx.x * 256 + 128 + c] = q;
    }
}

// reduce per-block partials (12500 x 256) -> csq[256]
__global__ __launch_bounds__(256) void stats2_kernel(
        const float* __restrict__ partial, float* __restrict__ csq) {
    int t = threadIdx.x;
    float s = 0.f;
    for (int b = blockIdx.x; b < NGB4; b += gridDim.x)
        s += partial[(size_t)b * 256 + t];
    unsafeAtomicAdd(&csq[t], s);
}

// ---------------------------------------------------------------------------
// One block per graph (batch is sorted): binary-search node range, compute
// layer-3 BN scale/shift inline from csq, mean-pool, 128->2 FC. No atomics.
// ---------------------------------------------------------------------------
__global__ __launch_bounds__(256) void pool_fc_kernel(
        const float* __restrict__ acc,
        const float* __restrict__ csq,
        const float* __restrict__ gamma, const float* __restrict__ beta,
        const int* __restrict__ batch,
        const float* __restrict__ Wfc, const float* __restrict__ bfc,
        float* __restrict__ out) {
    __shared__ float ps[256];
    int g = blockIdx.x;
    int lo = 0, hi = N_NODES;
    while (lo < hi) { int mid = (lo + hi) >> 1; if (batch[mid] < g) lo = mid + 1; else hi = mid; }
    int start = lo;
    hi = N_NODES;
    while (lo < hi) { int mid = (lo + hi) >> 1; if (batch[mid] < g + 1) lo = mid + 1; else hi = mid; }
    int end = lo;

    int c = threadIdx.x & 127;
    int half = threadIdx.x >> 7;
    const float invN = 1.0f / (float)N_NODES;
    float mu = csq[c] * invN;
    float var = csq[128 + c] * invN - mu * mu;
    float sc = gamma[c] * rsqrtf(var + BN_EPS);
    float sh = beta[c] - mu * sc;
    float s = 0.f;
    for (int r = start + half; r < end; r += 2)
        s += fmaxf(0.f, acc[r * 128 + c] * sc + sh);
    ps[threadIdx.x] = s;
    __syncthreads();
    if (half == 0)
        ps[c] = (ps[c] + ps[c + 128]) / fmaxf((float)(end - start), 1.0f);
    __syncthreads();
    if (threadIdx.x < 2) {
        int o = threadIdx.x;
        float t = 0.f;
        #pragma unroll 16
        for (int cc = 0; cc < 128; ++cc) t += ps[cc] * Wfc[cc * 2 + o];
        out[g * 2 + o] = t + bfc[o];
    }
}

// ---------------------------------------------------------------------------
extern "C" void kernel_launch(void* const* d_in, const int* in_sizes, int n_in,
                              void* d_out, int out_size, void* d_ws, size_t ws_size,
                              hipStream_t stream) {
    const float* x         = (const float*)d_in[0];
    const float* edge_attr = (const float*)d_in[1];
    const int*   eidx      = (const int*)d_in[2];
    const int*   batch     = (const int*)d_in[3];
    const float* Wn[3]  = {(const float*)d_in[4],  (const float*)d_in[8],  (const float*)d_in[12]};
    const float* bnb[3] = {(const float*)d_in[5],  (const float*)d_in[9],  (const float*)d_in[13]};
    const float* We[3]  = {(const float*)d_in[6],  (const float*)d_in[10], (const float*)d_in[14]};
    const float* be[3]  = {(const float*)d_in[7],  (const float*)d_in[11], (const float*)d_in[15]};
    const float* gm[3]  = {(const float*)d_in[16], (const float*)d_in[18], (const float*)d_in[20]};
    const float* bt[3]  = {(const float*)d_in[17], (const float*)d_in[19], (const float*)d_in[21]};
    const float* Wfc = (const float*)d_in[22];
    const float* bfc = (const float*)d_in[23];
    float* out = (float*)d_out;

    char* p = (char*)d_ws;
    auto alloc = [&](size_t bytes) {
        char* q = p;
        p += (bytes + 255) & ~size_t(255);
        return q;
    };
    // --- zero-region: deg, cursor, csq contiguous (single memset) ---
    int*    deg    = (int*)alloc(sizeof(int) * N_NODES);
    int*    cursor = (int*)alloc(sizeof(int) * N_NODES);
    float*  csq    = (float*)alloc(sizeof(float) * 3 * 256);   // per-layer {sum,sumsq}
    size_t  zbytes = (size_t)((char*)csq + sizeof(float) * 3 * 256 - (char*)deg);
    // --- rest ---
    ushort* h16    = (ushort*)alloc(sizeof(ushort) * N_NODES * HID);      // bf16 h
    ushort* Eab    = (ushort*)alloc(sizeof(ushort) * N_NODES * EDGE_DIM); // bf16 Ea
    float*  accA   = (float*)alloc(sizeof(float) * N_NODES * HID);
    float*  accB   = (float*)alloc(sizeof(float) * N_NODES * HID);
    float*  part   = (float*)alloc(sizeof(float) * NGB4 * 256);           // gather stats partials
    int*    rowp   = (int*)alloc(sizeof(int) * (N_NODES + 1));
    uint64* csr_pk = (uint64*)alloc(sizeof(uint64) * N_EDGES);
    short8* Wnp[3]; short8* Wep[3];
    for (int l = 0; l < 3; ++l) {
        Wnp[l] = (short8*)alloc(sizeof(short8) * 2048);
        Wep[l] = (short8*)alloc(sizeof(short8) * 512);
    }

    hipMemsetAsync(deg, 0, zbytes, stream);

    pre_kernel<<<2530, 256, 0, stream>>>(eidx, deg,
        Wn[0], We[0], Wn[1], We[1], Wn[2], We[2],
        Wnp[0], Wep[0], Wnp[1], Wep[1], Wnp[2], Wep[2]);
    scan_kernel<<<NSCB, 256, 0, stream>>>(deg, rowp);
    fill_csr_kernel<<<(N_EDGES + 255) / 256, 256, 0, stream>>>(eidx, rowp, cursor, csr_pk);
    ea_gather_kernel<<<(N_NODES + 7) / 8, 256, 0, stream>>>(edge_attr, rowp, csr_pk, Eab);

    float* accs[3] = {accA, accB, accA};
    for (int l = 0; l < 3; ++l) {
        float* acc = accs[l];
        const float* Xin = (l == 0) ? x : accs[l - 1];
        if (l == 0) {
            gemm_mfma_kernel<false><<<(NGRP16 + 3) / 4, 256, 0, stream>>>(
                Xin, Wnp[l], bnb[l], Eab, Wep[l], be[l], deg,
                nullptr, nullptr, nullptr, h16, acc);
        } else {
            gemm_mfma_kernel<true><<<(NGRP16 + 3) / 4, 256, 0, stream>>>(
                Xin, Wnp[l], bnb[l], Eab, Wep[l], be[l], deg,
                csq + (l - 1) * 256, gm[l - 1], bt[l - 1], h16, acc);
        }
        gather_kernel<<<NGB4, 256, 0, stream>>>(
            (const uint32*)h16, rowp, csr_pk, acc, part);
        stats2_kernel<<<25, 256, 0, stream>>>(part, csq + l * 256);
    }
    pool_fc_kernel<<<NUM_GRAPHS, 256, 0, stream>>>(
        accs[2], csq + 2 * 256, gm[2], bt[2], batch, Wfc, bfc, out);
}

// Round 16
// 368.147 us; speedup vs baseline: 1.8526x; 1.8526x over previous
//
#include <hip/hip_runtime.h>

#define N_NODES 50000
#define N_EDGES 640000
#define HID 128
#define EDGE_DIM 32
#define NUM_GRAPHS 512
#define BN_EPS 1e-5f
#define NGRP16 3125    // N_NODES / 16 (exact)
#define NGB4 12500     // N_NODES / 4 (exact) — gather blocks
#define NSCB 49        // ceil(N_NODES/1024)

typedef unsigned int uint32;
typedef unsigned long long uint64;
typedef unsigned short ushort;
typedef __attribute__((ext_vector_type(8))) short short8;   // 8 bf16 (4 VGPR)
typedef __attribute__((ext_vector_type(4))) float f32x4;    // MFMA accum

// round-to-nearest-even f32 -> bf16 bits
__device__ inline ushort f2bf(float x) {
    uint32 u = __float_as_uint(x);
    return (ushort)((u + 0x7fff + ((u >> 16) & 1)) >> 16);
}

// ---------------------------------------------------------------------------
// Merged preprocessing: blocks [0,2500) histogram deg; blocks [2500,2530)
// pack the 3 layers' weights into MFMA fragment layout.
// ---------------------------------------------------------------------------
__global__ __launch_bounds__(256) void pre_kernel(
        const int* __restrict__ eidx, int* __restrict__ deg,
        const float* __restrict__ Wn0, const float* __restrict__ We0,
        const float* __restrict__ Wn1, const float* __restrict__ We1,
        const float* __restrict__ Wn2, const float* __restrict__ We2,
        short8* __restrict__ Wnp0, short8* __restrict__ Wep0,
        short8* __restrict__ Wnp1, short8* __restrict__ Wep1,
        short8* __restrict__ Wnp2, short8* __restrict__ Wep2) {
    int b = blockIdx.x;
    if (b < 2500) {
        int e = b * 256 + threadIdx.x;          // N_EDGES = 2500*256 exactly
        atomicAdd(&deg[eidx[N_EDGES + e]], 1);
        return;
    }
    int idx = b - 2500;                          // 0..29
    int layer = idx / 10;
    int t = (idx % 10) * 256 + threadIdx.x;      // 0..2559
    const float* Wn = (layer == 0) ? Wn0 : (layer == 1) ? Wn1 : Wn2;
    const float* We = (layer == 0) ? We0 : (layer == 1) ? We1 : We2;
    short8* Wnp = (layer == 0) ? Wnp0 : (layer == 1) ? Wnp1 : Wnp2;
    short8* Wep = (layer == 0) ? Wep0 : (layer == 1) ? Wep1 : Wep2;
    if (t < 2048) {
        int l = t & 63, rest = t >> 6;
        int kb = rest & 3, nt = rest >> 2;
        int col = nt * 16 + (l & 15);
        int k0 = kb * 32 + (l >> 4) * 8;
        short8 v;
        #pragma unroll
        for (int j = 0; j < 8; ++j) v[j] = (short)f2bf(Wn[(k0 + j) * 128 + col]);
        Wnp[t] = v;
    } else if (t < 2560) {
        int e = t - 2048;
        int l = e & 63, nt = e >> 6;
        int col = nt * 16 + (l & 15);
        int k0 = (l >> 4) * 8;
        short8 v;
        #pragma unroll
        for (int j = 0; j < 8; ++j) v[j] = (short)f2bf(We[(k0 + j) * 128 + col]);
        Wep[e] = v;
    }
}

// ---------------------------------------------------------------------------
// One-dispatch exclusive scan: each block redundantly sums deg[0 .. b*1024)
// ---------------------------------------------------------------------------
__global__ __launch_bounds__(256) void scan_kernel(const int* __restrict__ deg,
                                                   int* __restrict__ rowp) {
    __shared__ int red[256];
    int b = blockIdx.x, tid = threadIdx.x;
    int pre = 0;
    int limit = b * 1024;
    for (int i = tid; i < limit; i += 256) pre += deg[i];
    red[tid] = pre;
    __syncthreads();
    for (int off = 128; off > 0; off >>= 1) {
        if (tid < off) red[tid] += red[tid + off];
        __syncthreads();
    }
    int base = red[0];
    __syncthreads();
    int basei = b * 1024 + tid * 4;
    int v[4];
    int s = 0;
    #pragma unroll
    for (int j = 0; j < 4; ++j) {
        int i = basei + j;
        v[j] = (i < N_NODES) ? deg[i] : 0;
        s += v[j];
    }
    red[tid] = s;
    __syncthreads();
    for (int off = 1; off < 256; off <<= 1) {
        int t = (tid >= off) ? red[tid - off] : 0;
        __syncthreads();
        red[tid] += t;
        __syncthreads();
    }
    int excl = base + red[tid] - s;
    #pragma unroll
    for (int j = 0; j < 4; ++j) {
        int i = basei + j;
        if (i < N_NODES) rowp[i] = excl;
        excl += v[j];
    }
    if (b == 0 && tid == 0) rowp[N_NODES] = N_EDGES;
}

// ---------------------------------------------------------------------------
// CSR fill (packed): csr_pk[p] = (eid << 32) | src — one 8B scatter per edge
// ---------------------------------------------------------------------------
__global__ void fill_csr_kernel(const int* __restrict__ eidx,
                                const int* __restrict__ rowp,
                                int* __restrict__ cursor,
                                uint64* __restrict__ csr_pk) {
    int e = blockIdx.x * 256 + threadIdx.x;
    if (e >= N_EDGES) return;
    int d = eidx[N_EDGES + e];
    int pos = rowp[d] + atomicAdd(&cursor[d], 1);
    csr_pk[pos] = ((uint64)(uint32)e << 32) | (uint32)eidx[e];
}

// ---------------------------------------------------------------------------
// Eab[d] = bf16( sum of edge_attr rows with dst == d )   (GEMM A-operand)
// ---------------------------------------------------------------------------
__global__ __launch_bounds__(256) void ea_gather_kernel(
        const float* __restrict__ edge_attr,
        const int* __restrict__ rowp,
        const uint64* __restrict__ csr_pk,
        ushort* __restrict__ Eab) {
    int node = blockIdx.x * 8 + (threadIdx.x >> 5);
    int c = threadIdx.x & 31;
    if (node >= N_NODES) return;
    int beg = rowp[node], end = rowp[node + 1];
    float s0 = 0.f, s1 = 0.f, s2 = 0.f, s3 = 0.f;
    int p = beg;
    for (; p + 4 <= end; p += 4) {
        int e0 = (int)(csr_pk[p]     >> 32);
        int e1 = (int)(csr_pk[p + 1] >> 32);
        int e2 = (int)(csr_pk[p + 2] >> 32);
        int e3 = (int)(csr_pk[p + 3] >> 32);
        s0 += edge_attr[e0 * EDGE_DIM + c];
        s1 += edge_attr[e1 * EDGE_DIM + c];
        s2 += edge_attr[e2 * EDGE_DIM + c];
        s3 += edge_attr[e3 * EDGE_DIM + c];
    }
    for (; p < end; ++p)
        s0 += edge_attr[(int)(csr_pk[p] >> 32) * EDGE_DIM + c];
    Eab[node * EDGE_DIM + c] = f2bf((s0 + s1) + (s2 + s3));
}

// ---------------------------------------------------------------------------
// MFMA GEMM with self-computed BN (scale/shift derived from csq in LDS).
// ---------------------------------------------------------------------------
template <bool BN>
__global__ __launch_bounds__(256) void gemm_mfma_kernel(
        const float* __restrict__ X, const short8* __restrict__ Wnp,
        const float* __restrict__ bnb,
        const ushort* __restrict__ eab, const short8* __restrict__ Wep,
        const float* __restrict__ be, const int* __restrict__ deg,
        const float* __restrict__ csq,
        const float* __restrict__ gamma, const float* __restrict__ beta,
        ushort* __restrict__ h16, float* __restrict__ acc) {
    __shared__ __align__(16) float scs[128];
    __shared__ __align__(16) float shs[128];
    const int tid = threadIdx.x;
    if (BN) {
        if (tid < 128) {
            const float invN = 1.0f / (float)N_NODES;
            float mu = csq[tid] * invN;
            float var = csq[128 + tid] * invN - mu * mu;
            float sc = gamma[tid] * rsqrtf(var + BN_EPS);
            scs[tid] = sc;
            shs[tid] = beta[tid] - mu * sc;
        }
        __syncthreads();
    }

    const int wid = tid >> 6, L = tid & 63;
    const int g = blockIdx.x * 4 + wid;
    if (g >= NGRP16) return;                    // wave-uniform exit (after barrier)
    const int r0 = g * 16;
    const int m = L & 15, kq = L >> 4;

    short8 afr[4];
    const float* xrow = X + (size_t)(r0 + m) * 128 + kq * 8;
    #pragma unroll
    for (int kb = 0; kb < 4; ++kb) {
        float v[8];
        *(float4*)&v[0] = *(const float4*)(xrow + kb * 32);
        *(float4*)&v[4] = *(const float4*)(xrow + kb * 32 + 4);
        if (BN) {
            float s[8], h[8];
            *(float4*)&s[0] = *(const float4*)(scs + kb * 32 + kq * 8);
            *(float4*)&s[4] = *(const float4*)(scs + kb * 32 + kq * 8 + 4);
            *(float4*)&h[0] = *(const float4*)(shs + kb * 32 + kq * 8);
            *(float4*)&h[4] = *(const float4*)(shs + kb * 32 + kq * 8 + 4);
            #pragma unroll
            for (int j = 0; j < 8; ++j)
                v[j] = fmaxf(0.f, v[j] * s[j] + h[j]);
        }
        short8 a;
        #pragma unroll
        for (int j = 0; j < 8; ++j) a[j] = (short)f2bf(v[j]);
        afr[kb] = a;
    }

    f32x4 d[8];
    #pragma unroll
    for (int nt = 0; nt < 8; ++nt) d[nt] = (f32x4)(0.f);

    #pragma unroll
    for (int kb = 0; kb < 4; ++kb) {
        #pragma unroll
        for (int nt = 0; nt < 8; ++nt) {
            short8 b = Wnp[(nt * 4 + kb) * 64 + L];
            d[nt] = __builtin_amdgcn_mfma_f32_16x16x32_bf16(afr[kb], b, d[nt], 0, 0, 0);
        }
    }

    float bnv[8], bev[8];
    #pragma unroll
    for (int nt = 0; nt < 8; ++nt) {
        bnv[nt] = bnb[nt * 16 + m];
        bev[nt] = be[nt * 16 + m];
    }

    #pragma unroll
    for (int nt = 0; nt < 8; ++nt) {
        #pragma unroll
        for (int i = 0; i < 4; ++i)
            h16[(size_t)(r0 + kq * 4 + i) * 128 + nt * 16 + m] =
                f2bf(d[nt][i] + bnv[nt]);
    }

    short8 ae = *(const short8*)(eab + (size_t)(r0 + m) * 32 + kq * 8);
    #pragma unroll
    for (int nt = 0; nt < 8; ++nt)
        d[nt] = __builtin_amdgcn_mfma_f32_16x16x32_bf16(ae, Wep[nt * 64 + L], d[nt], 0, 0, 0);

    float dg[4];
    #pragma unroll
    for (int i = 0; i < 4; ++i) dg[i] = (float)deg[r0 + kq * 4 + i];

    #pragma unroll
    for (int nt = 0; nt < 8; ++nt) {
        #pragma unroll
        for (int i = 0; i < 4; ++i)
            acc[(size_t)(r0 + kq * 4 + i) * 128 + nt * 16 + m] =
                d[nt][i] + bnv[nt] + dg[i] * bev[nt];
    }
}

// ---------------------------------------------------------------------------
// acc[d] += sum over CSR edges of h_bf16[src]  — fused column stats.
// ONE NODE PER WAVE (4 per block, grid 12500): full gather TLP (50000 waves,
// 8-deep MLP each) + end-of-block LDS stats reduce (fusion costs ~nothing).
// ---------------------------------------------------------------------------
__global__ __launch_bounds__(256) void gather_kernel(
        const uint32* __restrict__ h32,      // 64 uints (=128 bf16) per row
        const int* __restrict__ rowp, const uint64* __restrict__ csr_pk,
        float* __restrict__ acc, float* __restrict__ partial) {
    __shared__ float red_s[4][128];
    __shared__ float red_q[4][128];
    int wid = threadIdx.x >> 6, lane = threadIdx.x & 63;
    int node = blockIdx.x * 4 + wid;             // < N_NODES (12500*4 exact)
    int beg = rowp[node], end = rowp[node + 1];
    float sx[8] = {0.f,0.f,0.f,0.f,0.f,0.f,0.f,0.f};
    float sy[8] = {0.f,0.f,0.f,0.f,0.f,0.f,0.f,0.f};
    int p = beg;
    for (; p + 8 <= end; p += 8) {
        uint32 v[8];
        #pragma unroll
        for (int j = 0; j < 8; ++j)
            v[j] = h32[(int)(uint32)csr_pk[p + j] * 64 + lane];
        #pragma unroll
        for (int j = 0; j < 8; ++j) {
            sx[j] += __uint_as_float(v[j] << 16);
            sy[j] += __uint_as_float(v[j] & 0xffff0000u);
        }
    }
    for (; p + 4 <= end; p += 4) {
        uint32 v[4];
        #pragma unroll
        for (int j = 0; j < 4; ++j)
            v[j] = h32[(int)(uint32)csr_pk[p + j] * 64 + lane];
        #pragma unroll
        for (int j = 0; j < 4; ++j) {
            sx[j] += __uint_as_float(v[j] << 16);
            sy[j] += __uint_as_float(v[j] & 0xffff0000u);
        }
    }
    for (; p < end; ++p) {
        uint32 v = h32[(int)(uint32)csr_pk[p] * 64 + lane];
        sx[0] += __uint_as_float(v << 16);
        sy[0] += __uint_as_float(v & 0xffff0000u);
    }
    float2* ap = (float2*)&acc[(size_t)node * 128 + lane * 2];
    float2 a = *ap;
    a.x += ((sx[0] + sx[1]) + (sx[2] + sx[3])) + ((sx[4] + sx[5]) + (sx[6] + sx[7]));
    a.y += ((sy[0] + sy[1]) + (sy[2] + sy[3])) + ((sy[4] + sy[5]) + (sy[6] + sy[7]));
    *ap = a;
    red_s[wid][lane * 2]     = a.x;
    red_s[wid][lane * 2 + 1] = a.y;
    red_q[wid][lane * 2]     = a.x * a.x;
    red_q[wid][lane * 2 + 1] = a.y * a.y;
    __syncthreads();
    int t = threadIdx.x;
    if (t < 128) {
        float s = (red_s[0][t] + red_s[1][t]) + (red_s[2][t] + red_s[3][t]);
        partial[(size_t)blockIdx.x * 256 + t] = s;
    } else {
        int c = t - 128;
        float q = (red_q[0][c] + red_q[1][c]) + (red_q[2][c] + red_q[3][c]);
        partial[(size_t)blockIdx.x * 256 + 128 + c] = q;
    }
}

// reduce per-block partials (12500 x 256) -> csq[256]
// 256 blocks: each strides the 12500 rows (coalesced 1KB reads), 1 atomic/lane
__global__ __launch_bounds__(256) void stats2_kernel(
        const float* __restrict__ partial, float* __restrict__ csq) {
    int t = threadIdx.x;
    float s = 0.f;
    for (int b = blockIdx.x; b < NGB4; b += gridDim.x)
        s += partial[(size_t)b * 256 + t];
    unsafeAtomicAdd(&csq[t], s);
}

// ---------------------------------------------------------------------------
// One block per graph (batch is sorted): binary-search node range, compute
// layer-3 BN scale/shift inline from csq, mean-pool, 128->2 FC. No atomics.
// ---------------------------------------------------------------------------
__global__ __launch_bounds__(256) void pool_fc_kernel(
        const float* __restrict__ acc,
        const float* __restrict__ csq,
        const float* __restrict__ gamma, const float* __restrict__ beta,
        const int* __restrict__ batch,
        const float* __restrict__ Wfc, const float* __restrict__ bfc,
        float* __restrict__ out) {
    __shared__ float ps[256];
    int g = blockIdx.x;
    int lo = 0, hi = N_NODES;
    while (lo < hi) { int mid = (lo + hi) >> 1; if (batch[mid] < g) lo = mid + 1; else hi = mid; }
    int start = lo;
    hi = N_NODES;
    while (lo < hi) { int mid = (lo + hi) >> 1; if (batch[mid] < g + 1) lo = mid + 1; else hi = mid; }
    int end = lo;

    int c = threadIdx.x & 127;
    int half = threadIdx.x >> 7;
    const float invN = 1.0f / (float)N_NODES;
    float mu = csq[c] * invN;
    float var = csq[128 + c] * invN - mu * mu;
    float sc = gamma[c] * rsqrtf(var + BN_EPS);
    float sh = beta[c] - mu * sc;
    float s = 0.f;
    for (int r = start + half; r < end; r += 2)
        s += fmaxf(0.f, acc[r * 128 + c] * sc + sh);
    ps[threadIdx.x] = s;
    __syncthreads();
    if (half == 0)
        ps[c] = (ps[c] + ps[c + 128]) / fmaxf((float)(end - start), 1.0f);
    __syncthreads();
    if (threadIdx.x < 2) {
        int o = threadIdx.x;
        float t = 0.f;
        #pragma unroll 16
        for (int cc = 0; cc < 128; ++cc) t += ps[cc] * Wfc[cc * 2 + o];
        out[g * 2 + o] = t + bfc[o];
    }
}

// ---------------------------------------------------------------------------
extern "C" void kernel_launch(void* const* d_in, const int* in_sizes, int n_in,
                              void* d_out, int out_size, void* d_ws, size_t ws_size,
                              hipStream_t stream) {
    const float* x         = (const float*)d_in[0];
    const float* edge_attr = (const float*)d_in[1];
    const int*   eidx      = (const int*)d_in[2];
    const int*   batch     = (const int*)d_in[3];
    const float* Wn[3]  = {(const float*)d_in[4],  (const float*)d_in[8],  (const float*)d_in[12]};
    const float* bnb[3] = {(const float*)d_in[5],  (const float*)d_in[9],  (const float*)d_in[13]};
    const float* We[3]  = {(const float*)d_in[6],  (const float*)d_in[10], (const float*)d_in[14]};
    const float* be[3]  = {(const float*)d_in[7],  (const float*)d_in[11], (const float*)d_in[15]};
    const float* gm[3]  = {(const float*)d_in[16], (const float*)d_in[18], (const float*)d_in[20]};
    const float* bt[3]  = {(const float*)d_in[17], (const float*)d_in[19], (const float*)d_in[21]};
    const float* Wfc = (const float*)d_in[22];
    const float* bfc = (const float*)d_in[23];
    float* out = (float*)d_out;

    char* p = (char*)d_ws;
    auto alloc = [&](size_t bytes) {
        char* q = p;
        p += (bytes + 255) & ~size_t(255);
        return q;
    };
    // --- zero-region: deg, cursor, csq contiguous (single memset) ---
    int*    deg    = (int*)alloc(sizeof(int) * N_NODES);
    int*    cursor = (int*)alloc(sizeof(int) * N_NODES);
    float*  csq    = (float*)alloc(sizeof(float) * 3 * 256);   // per-layer {sum,sumsq}
    size_t  zbytes = (size_t)((char*)csq + sizeof(float) * 3 * 256 - (char*)deg);
    // --- rest ---
    ushort* h16    = (ushort*)alloc(sizeof(ushort) * N_NODES * HID);      // bf16 h
    ushort* Eab    = (ushort*)alloc(sizeof(ushort) * N_NODES * EDGE_DIM); // bf16 Ea
    float*  accA   = (float*)alloc(sizeof(float) * N_NODES * HID);
    float*  accB   = (float*)alloc(sizeof(float) * N_NODES * HID);
    float*  part   = (float*)alloc(sizeof(float) * NGB4 * 256);           // gather stats partials
    int*    rowp   = (int*)alloc(sizeof(int) * (N_NODES + 1));
    uint64* csr_pk = (uint64*)alloc(sizeof(uint64) * N_EDGES);
    short8* Wnp[3]; short8* Wep[3];
    for (int l = 0; l < 3; ++l) {
        Wnp[l] = (short8*)alloc(sizeof(short8) * 2048);
        Wep[l] = (short8*)alloc(sizeof(short8) * 512);
    }

    hipMemsetAsync(deg, 0, zbytes, stream);

    pre_kernel<<<2530, 256, 0, stream>>>(eidx, deg,
        Wn[0], We[0], Wn[1], We[1], Wn[2], We[2],
        Wnp[0], Wep[0], Wnp[1], Wep[1], Wnp[2], Wep[2]);
    scan_kernel<<<NSCB, 256, 0, stream>>>(deg, rowp);
    fill_csr_kernel<<<(N_EDGES + 255) / 256, 256, 0, stream>>>(eidx, rowp, cursor, csr_pk);
    ea_gather_kernel<<<(N_NODES + 7) / 8, 256, 0, stream>>>(edge_attr, rowp, csr_pk, Eab);

    float* accs[3] = {accA, accB, accA};
    for (int l = 0; l < 3; ++l) {
        float* acc = accs[l];
        const float* Xin = (l == 0) ? x : accs[l - 1];
        if (l == 0) {
            gemm_mfma_kernel<false><<<(NGRP16 + 3) / 4, 256, 0, stream>>>(
                Xin, Wnp[l], bnb[l], Eab, Wep[l], be[l], deg,
                nullptr, nullptr, nullptr, h16, acc);
        } else {
            gemm_mfma_kernel<true><<<(NGRP16 + 3) / 4, 256, 0, stream>>>(
                Xin, Wnp[l], bnb[l], Eab, Wep[l], be[l], deg,
                csq + (l - 1) * 256, gm[l - 1], bt[l - 1], h16, acc);
        }
        gather_kernel<<<NGB4, 256, 0, stream>>>(
            (const uint32*)h16, rowp, csr_pk, acc, part);
        stats2_kernel<<<256, 256, 0, stream>>>(part, csq + l * 256);
    }
    pool_fc_kernel<<<NUM_GRAPHS, 256, 0, stream>>>(
        accs[2], csq + 2 * 256, gm[2], bt[2], batch, Wfc, bfc, out);
}

// Round 17
// 340.083 us; speedup vs baseline: 2.0055x; 1.0825x over previous
//
#include <hip/hip_runtime.h>

#define N_NODES 50000
#define N_EDGES 640000
#define HID 128
#define EDGE_DIM 32
#define NUM_GRAPHS 512
#define BN_EPS 1e-5f
#define NGRP16 3125    // N_NODES / 16 (exact)
#define NGB4 12500     // N_NODES / 4 (exact) — gather blocks
#define NSCB 49        // ceil(N_NODES/1024)

typedef unsigned int uint32;
typedef unsigned long long uint64;
typedef unsigned short ushort;
typedef __attribute__((ext_vector_type(8))) short short8;   // 8 bf16 (4 VGPR)
typedef __attribute__((ext_vector_type(4))) float f32x4;    // MFMA accum

// round-to-nearest-even f32 -> bf16 bits
__device__ inline ushort f2bf(float x) {
    uint32 u = __float_as_uint(x);
    return (ushort)((u + 0x7fff + ((u >> 16) & 1)) >> 16);
}

// ---------------------------------------------------------------------------
// Merged preprocessing: blocks [0,2500) histogram deg AND record each edge's
// rank within its dst bucket (the atomic's return value — fill_csr then
// needs no atomics); blocks [2500,2530) pack the 3 layers' weights.
// ---------------------------------------------------------------------------
__global__ __launch_bounds__(256) void pre_kernel(
        const int* __restrict__ eidx, int* __restrict__ deg,
        int* __restrict__ rank,
        const float* __restrict__ Wn0, const float* __restrict__ We0,
        const float* __restrict__ Wn1, const float* __restrict__ We1,
        const float* __restrict__ Wn2, const float* __restrict__ We2,
        short8* __restrict__ Wnp0, short8* __restrict__ Wep0,
        short8* __restrict__ Wnp1, short8* __restrict__ Wep1,
        short8* __restrict__ Wnp2, short8* __restrict__ Wep2) {
    int b = blockIdx.x;
    if (b < 2500) {
        int e = b * 256 + threadIdx.x;          // N_EDGES = 2500*256 exactly
        int d = eidx[N_EDGES + e];
        rank[e] = atomicAdd(&deg[d], 1);
        return;
    }
    int idx = b - 2500;                          // 0..29
    int layer = idx / 10;
    int t = (idx % 10) * 256 + threadIdx.x;      // 0..2559
    const float* Wn = (layer == 0) ? Wn0 : (layer == 1) ? Wn1 : Wn2;
    const float* We = (layer == 0) ? We0 : (layer == 1) ? We1 : We2;
    short8* Wnp = (layer == 0) ? Wnp0 : (layer == 1) ? Wnp1 : Wnp2;
    short8* Wep = (layer == 0) ? Wep0 : (layer == 1) ? Wep1 : Wep2;
    if (t < 2048) {
        int l = t & 63, rest = t >> 6;
        int kb = rest & 3, nt = rest >> 2;
        int col = nt * 16 + (l & 15);
        int k0 = kb * 32 + (l >> 4) * 8;
        short8 v;
        #pragma unroll
        for (int j = 0; j < 8; ++j) v[j] = (short)f2bf(Wn[(k0 + j) * 128 + col]);
        Wnp[t] = v;
    } else if (t < 2560) {
        int e = t - 2048;
        int l = e & 63, nt = e >> 6;
        int col = nt * 16 + (l & 15);
        int k0 = (l >> 4) * 8;
        short8 v;
        #pragma unroll
        for (int j = 0; j < 8; ++j) v[j] = (short)f2bf(We[(k0 + j) * 128 + col]);
        Wep[e] = v;
    }
}

// ---------------------------------------------------------------------------
// One-dispatch exclusive scan: each block redundantly sums deg[0 .. b*1024)
// ---------------------------------------------------------------------------
__global__ __launch_bounds__(256) void scan_kernel(const int* __restrict__ deg,
                                                   int* __restrict__ rowp) {
    __shared__ int red[256];
    int b = blockIdx.x, tid = threadIdx.x;
    int pre = 0;
    int limit = b * 1024;
    for (int i = tid; i < limit; i += 256) pre += deg[i];
    red[tid] = pre;
    __syncthreads();
    for (int off = 128; off > 0; off >>= 1) {
        if (tid < off) red[tid] += red[tid + off];
        __syncthreads();
    }
    int base = red[0];
    __syncthreads();
    int basei = b * 1024 + tid * 4;
    int v[4];
    int s = 0;
    #pragma unroll
    for (int j = 0; j < 4; ++j) {
        int i = basei + j;
        v[j] = (i < N_NODES) ? deg[i] : 0;
        s += v[j];
    }
    red[tid] = s;
    __syncthreads();
    for (int off = 1; off < 256; off <<= 1) {
        int t = (tid >= off) ? red[tid - off] : 0;
        __syncthreads();
        red[tid] += t;
        __syncthreads();
    }
    int excl = base + red[tid] - s;
    #pragma unroll
    for (int j = 0; j < 4; ++j) {
        int i = basei + j;
        if (i < N_NODES) rowp[i] = excl;
        excl += v[j];
    }
    if (b == 0 && tid == 0) rowp[N_NODES] = N_EDGES;
}

// ---------------------------------------------------------------------------
// CSR fill, ATOMIC-FREE: rank was captured during the histogram.
// csr_pk[rowp[d] + rank[e]] = (eid << 32) | src
// ---------------------------------------------------------------------------
__global__ void fill_csr_kernel(const int* __restrict__ eidx,
                                const int* __restrict__ rowp,
                                const int* __restrict__ rank,
                                uint64* __restrict__ csr_pk) {
    int e = blockIdx.x * 256 + threadIdx.x;
    if (e >= N_EDGES) return;
    int d = eidx[N_EDGES + e];
    csr_pk[rowp[d] + rank[e]] = ((uint64)(uint32)e << 32) | (uint32)eidx[e];
}

// ---------------------------------------------------------------------------
// Eab[d] = bf16( sum of edge_attr rows with dst == d )   (GEMM A-operand)
// ---------------------------------------------------------------------------
__global__ __launch_bounds__(256) void ea_gather_kernel(
        const float* __restrict__ edge_attr,
        const int* __restrict__ rowp,
        const uint64* __restrict__ csr_pk,
        ushort* __restrict__ Eab) {
    int node = blockIdx.x * 8 + (threadIdx.x >> 5);
    int c = threadIdx.x & 31;
    if (node >= N_NODES) return;
    int beg = rowp[node], end = rowp[node + 1];
    float s0 = 0.f, s1 = 0.f, s2 = 0.f, s3 = 0.f;
    int p = beg;
    for (; p + 4 <= end; p += 4) {
        int e0 = (int)(csr_pk[p]     >> 32);
        int e1 = (int)(csr_pk[p + 1] >> 32);
        int e2 = (int)(csr_pk[p + 2] >> 32);
        int e3 = (int)(csr_pk[p + 3] >> 32);
        s0 += edge_attr[e0 * EDGE_DIM + c];
        s1 += edge_attr[e1 * EDGE_DIM + c];
        s2 += edge_attr[e2 * EDGE_DIM + c];
        s3 += edge_attr[e3 * EDGE_DIM + c];
    }
    for (; p < end; ++p)
        s0 += edge_attr[(int)(csr_pk[p] >> 32) * EDGE_DIM + c];
    Eab[node * EDGE_DIM + c] = f2bf((s0 + s1) + (s2 + s3));
}

// ---------------------------------------------------------------------------
// MFMA GEMM with self-computed BN (scale/shift derived from csq in LDS).
// ---------------------------------------------------------------------------
template <bool BN>
__global__ __launch_bounds__(256) void gemm_mfma_kernel(
        const float* __restrict__ X, const short8* __restrict__ Wnp,
        const float* __restrict__ bnb,
        const ushort* __restrict__ eab, const short8* __restrict__ Wep,
        const float* __restrict__ be, const int* __restrict__ deg,
        const float* __restrict__ csq,
        const float* __restrict__ gamma, const float* __restrict__ beta,
        ushort* __restrict__ h16, float* __restrict__ acc) {
    __shared__ __align__(16) float scs[128];
    __shared__ __align__(16) float shs[128];
    const int tid = threadIdx.x;
    if (BN) {
        if (tid < 128) {
            const float invN = 1.0f / (float)N_NODES;
            float mu = csq[tid] * invN;
            float var = csq[128 + tid] * invN - mu * mu;
            float sc = gamma[tid] * rsqrtf(var + BN_EPS);
            scs[tid] = sc;
            shs[tid] = beta[tid] - mu * sc;
        }
        __syncthreads();
    }

    const int wid = tid >> 6, L = tid & 63;
    const int g = blockIdx.x * 4 + wid;
    if (g >= NGRP16) return;                    // wave-uniform exit (after barrier)
    const int r0 = g * 16;
    const int m = L & 15, kq = L >> 4;

    short8 afr[4];
    const float* xrow = X + (size_t)(r0 + m) * 128 + kq * 8;
    #pragma unroll
    for (int kb = 0; kb < 4; ++kb) {
        float v[8];
        *(float4*)&v[0] = *(const float4*)(xrow + kb * 32);
        *(float4*)&v[4] = *(const float4*)(xrow + kb * 32 + 4);
        if (BN) {
            float s[8], h[8];
            *(float4*)&s[0] = *(const float4*)(scs + kb * 32 + kq * 8);
            *(float4*)&s[4] = *(const float4*)(scs + kb * 32 + kq * 8 + 4);
            *(float4*)&h[0] = *(const float4*)(shs + kb * 32 + kq * 8);
            *(float4*)&h[4] = *(const float4*)(shs + kb * 32 + kq * 8 + 4);
            #pragma unroll
            for (int j = 0; j < 8; ++j)
                v[j] = fmaxf(0.f, v[j] * s[j] + h[j]);
        }
        short8 a;
        #pragma unroll
        for (int j = 0; j < 8; ++j) a[j] = (short)f2bf(v[j]);
        afr[kb] = a;
    }

    f32x4 d[8];
    #pragma unroll
    for (int nt = 0; nt < 8; ++nt) d[nt] = (f32x4)(0.f);

    #pragma unroll
    for (int kb = 0; kb < 4; ++kb) {
        #pragma unroll
        for (int nt = 0; nt < 8; ++nt) {
            short8 b = Wnp[(nt * 4 + kb) * 64 + L];
            d[nt] = __builtin_amdgcn_mfma_f32_16x16x32_bf16(afr[kb], b, d[nt], 0, 0, 0);
        }
    }

    float bnv[8], bev[8];
    #pragma unroll
    for (int nt = 0; nt < 8; ++nt) {
        bnv[nt] = bnb[nt * 16 + m];
        bev[nt] = be[nt * 16 + m];
    }

    #pragma unroll
    for (int nt = 0; nt < 8; ++nt) {
        #pragma unroll
        for (int i = 0; i < 4; ++i)
            h16[(size_t)(r0 + kq * 4 + i) * 128 + nt * 16 + m] =
                f2bf(d[nt][i] + bnv[nt]);
    }

    short8 ae = *(const short8*)(eab + (size_t)(r0 + m) * 32 + kq * 8);
    #pragma unroll
    for (int nt = 0; nt < 8; ++nt)
        d[nt] = __builtin_amdgcn_mfma_f32_16x16x32_bf16(ae, Wep[nt * 64 + L], d[nt], 0, 0, 0);

    float dg[4];
    #pragma unroll
    for (int i = 0; i < 4; ++i) dg[i] = (float)deg[r0 + kq * 4 + i];

    #pragma unroll
    for (int nt = 0; nt < 8; ++nt) {
        #pragma unroll
        for (int i = 0; i < 4; ++i)
            acc[(size_t)(r0 + kq * 4 + i) * 128 + nt * 16 + m] =
                d[nt][i] + bnv[nt] + dg[i] * bev[nt];
    }
}

// ---------------------------------------------------------------------------
// acc[d] += sum over CSR edges of h_bf16[src]  — fused column stats.
// ONE NODE PER WAVE (4 per block, grid 12500): full gather TLP + end-of-block
// LDS stats reduce into per-block partials.
// ---------------------------------------------------------------------------
__global__ __launch_bounds__(256) void gather_kernel(
        const uint32* __restrict__ h32,      // 64 uints (=128 bf16) per row
        const int* __restrict__ rowp, const uint64* __restrict__ csr_pk,
        float* __restrict__ acc, float* __restrict__ partial) {
    __shared__ float red_s[4][128];
    __shared__ float red_q[4][128];
    int wid = threadIdx.x >> 6, lane = threadIdx.x & 63;
    int node = blockIdx.x * 4 + wid;             // < N_NODES (12500*4 exact)
    int beg = rowp[node], end = rowp[node + 1];
    float sx[8] = {0.f,0.f,0.f,0.f,0.f,0.f,0.f,0.f};
    float sy[8] = {0.f,0.f,0.f,0.f,0.f,0.f,0.f,0.f};
    int p = beg;
    for (; p + 8 <= end; p += 8) {
        uint32 v[8];
        #pragma unroll
        for (int j = 0; j < 8; ++j)
            v[j] = h32[(int)(uint32)csr_pk[p + j] * 64 + lane];
        #pragma unroll
        for (int j = 0; j < 8; ++j) {
            sx[j] += __uint_as_float(v[j] << 16);
            sy[j] += __uint_as_float(v[j] & 0xffff0000u);
        }
    }
    for (; p + 4 <= end; p += 4) {
        uint32 v[4];
        #pragma unroll
        for (int j = 0; j < 4; ++j)
            v[j] = h32[(int)(uint32)csr_pk[p + j] * 64 + lane];
        #pragma unroll
        for (int j = 0; j < 4; ++j) {
            sx[j] += __uint_as_float(v[j] << 16);
            sy[j] += __uint_as_float(v[j] & 0xffff0000u);
        }
    }
    for (; p < end; ++p) {
        uint32 v = h32[(int)(uint32)csr_pk[p] * 64 + lane];
        sx[0] += __uint_as_float(v << 16);
        sy[0] += __uint_as_float(v & 0xffff0000u);
    }
    float2* ap = (float2*)&acc[(size_t)node * 128 + lane * 2];
    float2 a = *ap;
    a.x += ((sx[0] + sx[1]) + (sx[2] + sx[3])) + ((sx[4] + sx[5]) + (sx[6] + sx[7]));
    a.y += ((sy[0] + sy[1]) + (sy[2] + sy[3])) + ((sy[4] + sy[5]) + (sy[6] + sy[7]));
    *ap = a;
    red_s[wid][lane * 2]     = a.x;
    red_s[wid][lane * 2 + 1] = a.y;
    red_q[wid][lane * 2]     = a.x * a.x;
    red_q[wid][lane * 2 + 1] = a.y * a.y;
    __syncthreads();
    int t = threadIdx.x;
    if (t < 128) {
        float s = (red_s[0][t] + red_s[1][t]) + (red_s[2][t] + red_s[3][t]);
        partial[(size_t)blockIdx.x * 256 + t] = s;
    } else {
        int c = t - 128;
        float q = (red_q[0][c] + red_q[1][c]) + (red_q[2][c] + red_q[3][c]);
        partial[(size_t)blockIdx.x * 256 + 128 + c] = q;
    }
}

// reduce per-block partials (12500 x 256) -> csq[256]
// 256 blocks: each strides the 12500 rows (coalesced 1KB reads), 1 atomic/lane
__global__ __launch_bounds__(256) void stats2_kernel(
        const float* __restrict__ partial, float* __restrict__ csq) {
    int t = threadIdx.x;
    float s = 0.f;
    for (int b = blockIdx.x; b < NGB4; b += gridDim.x)
        s += partial[(size_t)b * 256 + t];
    unsafeAtomicAdd(&csq[t], s);
}

// ---------------------------------------------------------------------------
// One block per graph (batch is sorted): binary-search node range, compute
// layer-3 BN scale/shift inline from csq, mean-pool, 128->2 FC. No atomics.
// ---------------------------------------------------------------------------
__global__ __launch_bounds__(256) void pool_fc_kernel(
        const float* __restrict__ acc,
        const float* __restrict__ csq,
        const float* __restrict__ gamma, const float* __restrict__ beta,
        const int* __restrict__ batch,
        const float* __restrict__ Wfc, const float* __restrict__ bfc,
        float* __restrict__ out) {
    __shared__ float ps[256];
    int g = blockIdx.x;
    int lo = 0, hi = N_NODES;
    while (lo < hi) { int mid = (lo + hi) >> 1; if (batch[mid] < g) lo = mid + 1; else hi = mid; }
    int start = lo;
    hi = N_NODES;
    while (lo < hi) { int mid = (lo + hi) >> 1; if (batch[mid] < g + 1) lo = mid + 1; else hi = mid; }
    int end = lo;

    int c = threadIdx.x & 127;
    int half = threadIdx.x >> 7;
    const float invN = 1.0f / (float)N_NODES;
    float mu = csq[c] * invN;
    float var = csq[128 + c] * invN - mu * mu;
    float sc = gamma[c] * rsqrtf(var + BN_EPS);
    float sh = beta[c] - mu * sc;
    float s = 0.f;
    for (int r = start + half; r < end; r += 2)
        s += fmaxf(0.f, acc[r * 128 + c] * sc + sh);
    ps[threadIdx.x] = s;
    __syncthreads();
    if (half == 0)
        ps[c] = (ps[c] + ps[c + 128]) / fmaxf((float)(end - start), 1.0f);
    __syncthreads();
    if (threadIdx.x < 2) {
        int o = threadIdx.x;
        float t = 0.f;
        #pragma unroll 16
        for (int cc = 0; cc < 128; ++cc) t += ps[cc] * Wfc[cc * 2 + o];
        out[g * 2 + o] = t + bfc[o];
    }
}

// ---------------------------------------------------------------------------
extern "C" void kernel_launch(void* const* d_in, const int* in_sizes, int n_in,
                              void* d_out, int out_size, void* d_ws, size_t ws_size,
                              hipStream_t stream) {
    const float* x         = (const float*)d_in[0];
    const float* edge_attr = (const float*)d_in[1];
    const int*   eidx      = (const int*)d_in[2];
    const int*   batch     = (const int*)d_in[3];
    const float* Wn[3]  = {(const float*)d_in[4],  (const float*)d_in[8],  (const float*)d_in[12]};
    const float* bnb[3] = {(const float*)d_in[5],  (const float*)d_in[9],  (const float*)d_in[13]};
    const float* We[3]  = {(const float*)d_in[6],  (const float*)d_in[10], (const float*)d_in[14]};
    const float* be[3]  = {(const float*)d_in[7],  (const float*)d_in[11], (const float*)d_in[15]};
    const float* gm[3]  = {(const float*)d_in[16], (const float*)d_in[18], (const float*)d_in[20]};
    const float* bt[3]  = {(const float*)d_in[17], (const float*)d_in[19], (const float*)d_in[21]};
    const float* Wfc = (const float*)d_in[22];
    const float* bfc = (const float*)d_in[23];
    float* out = (float*)d_out;

    char* p = (char*)d_ws;
    auto alloc = [&](size_t bytes) {
        char* q = p;
        p += (bytes + 255) & ~size_t(255);
        return q;
    };
    // --- zero-region: deg, csq contiguous (single memset) ---
    int*    deg    = (int*)alloc(sizeof(int) * N_NODES);
    float*  csq    = (float*)alloc(sizeof(float) * 3 * 256);   // per-layer {sum,sumsq}
    size_t  zbytes = (size_t)((char*)csq + sizeof(float) * 3 * 256 - (char*)deg);
    // --- rest ---
    int*    rank   = (int*)alloc(sizeof(int) * N_EDGES);
    ushort* h16    = (ushort*)alloc(sizeof(ushort) * N_NODES * HID);      // bf16 h
    ushort* Eab    = (ushort*)alloc(sizeof(ushort) * N_NODES * EDGE_DIM); // bf16 Ea
    float*  accA   = (float*)alloc(sizeof(float) * N_NODES * HID);
    float*  accB   = (float*)alloc(sizeof(float) * N_NODES * HID);
    float*  part   = (float*)alloc(sizeof(float) * NGB4 * 256);           // gather stats partials
    int*    rowp   = (int*)alloc(sizeof(int) * (N_NODES + 1));
    uint64* csr_pk = (uint64*)alloc(sizeof(uint64) * N_EDGES);
    short8* Wnp[3]; short8* Wep[3];
    for (int l = 0; l < 3; ++l) {
        Wnp[l] = (short8*)alloc(sizeof(short8) * 2048);
        Wep[l] = (short8*)alloc(sizeof(short8) * 512);
    }

    hipMemsetAsync(deg, 0, zbytes, stream);

    pre_kernel<<<2530, 256, 0, stream>>>(eidx, deg, rank,
        Wn[0], We[0], Wn[1], We[1], Wn[2], We[2],
        Wnp[0], Wep[0], Wnp[1], Wep[1], Wnp[2], Wep[2]);
    scan_kernel<<<NSCB, 256, 0, stream>>>(deg, rowp);
    fill_csr_kernel<<<(N_EDGES + 255) / 256, 256, 0, stream>>>(eidx, rowp, rank, csr_pk);
    ea_gather_kernel<<<(N_NODES + 7) / 8, 256, 0, stream>>>(edge_attr, rowp, csr_pk, Eab);

    float* accs[3] = {accA, accB, accA};
    for (int l = 0; l < 3; ++l) {
        float* acc = accs[l];
        const float* Xin = (l == 0) ? x : accs[l - 1];
        if (l == 0) {
            gemm_mfma_kernel<false><<<(NGRP16 + 3) / 4, 256, 0, stream>>>(
                Xin, Wnp[l], bnb[l], Eab, Wep[l], be[l], deg,
                nullptr, nullptr, nullptr, h16, acc);
        } else {
            gemm_mfma_kernel<true><<<(NGRP16 + 3) / 4, 256, 0, stream>>>(
                Xin, Wnp[l], bnb[l], Eab, Wep[l], be[l], deg,
                csq + (l - 1) * 256, gm[l - 1], bt[l - 1], h16, acc);
        }
        gather_kernel<<<NGB4, 256, 0, stream>>>(
            (const uint32*)h16, rowp, csr_pk, acc, part);
        stats2_kernel<<<256, 256, 0, stream>>>(part, csq + l * 256);
    }
    pool_fc_kernel<<<NUM_GRAPHS, 256, 0, stream>>>(
        accs[2], csq + 2 * 256, gm[2], bt[2], batch, Wfc, bfc, out);
}

// Round 18
// 297.087 us; speedup vs baseline: 2.2957x; 1.1447x over previous
//
#include <hip/hip_runtime.h>

#define N_NODES 50000
#define N_EDGES 640000
#define HID 128
#define EDGE_DIM 32
#define NUM_GRAPHS 512
#define BN_EPS 1e-5f
#define NGRP16 3125    // N_NODES / 16 (exact)
#define NGB4 12500     // N_NODES / 4 (exact) — gather blocks
#define NSCB 49        // ceil(N_NODES/1024)
#define NREP 32        // csq replicas (bounds per-address atomic depth)

typedef unsigned int uint32;
typedef unsigned long long uint64;
typedef unsigned short ushort;
typedef __attribute__((ext_vector_type(8))) short short8;   // 8 bf16 (4 VGPR)
typedef __attribute__((ext_vector_type(4))) float f32x4;    // MFMA accum

// round-to-nearest-even f32 -> bf16 bits
__device__ inline ushort f2bf(float x) {
    uint32 u = __float_as_uint(x);
    return (ushort)((u + 0x7fff + ((u >> 16) & 1)) >> 16);
}

// ---------------------------------------------------------------------------
// Merged preprocessing: blocks [0,2500) histogram deg AND record each edge's
// rank within its dst bucket; blocks [2500,2530) pack the 3 layers' weights.
// ---------------------------------------------------------------------------
__global__ __launch_bounds__(256) void pre_kernel(
        const int* __restrict__ eidx, int* __restrict__ deg,
        int* __restrict__ rank,
        const float* __restrict__ Wn0, const float* __restrict__ We0,
        const float* __restrict__ Wn1, const float* __restrict__ We1,
        const float* __restrict__ Wn2, const float* __restrict__ We2,
        short8* __restrict__ Wnp0, short8* __restrict__ Wep0,
        short8* __restrict__ Wnp1, short8* __restrict__ Wep1,
        short8* __restrict__ Wnp2, short8* __restrict__ Wep2) {
    int b = blockIdx.x;
    if (b < 2500) {
        int e = b * 256 + threadIdx.x;          // N_EDGES = 2500*256 exactly
        int d = eidx[N_EDGES + e];
        rank[e] = atomicAdd(&deg[d], 1);
        return;
    }
    int idx = b - 2500;                          // 0..29
    int layer = idx / 10;
    int t = (idx % 10) * 256 + threadIdx.x;      // 0..2559
    const float* Wn = (layer == 0) ? Wn0 : (layer == 1) ? Wn1 : Wn2;
    const float* We = (layer == 0) ? We0 : (layer == 1) ? We1 : We2;
    short8* Wnp = (layer == 0) ? Wnp0 : (layer == 1) ? Wnp1 : Wnp2;
    short8* Wep = (layer == 0) ? Wep0 : (layer == 1) ? Wep1 : Wep2;
    if (t < 2048) {
        int l = t & 63, rest = t >> 6;
        int kb = rest & 3, nt = rest >> 2;
        int col = nt * 16 + (l & 15);
        int k0 = kb * 32 + (l >> 4) * 8;
        short8 v;
        #pragma unroll
        for (int j = 0; j < 8; ++j) v[j] = (short)f2bf(Wn[(k0 + j) * 128 + col]);
        Wnp[t] = v;
    } else if (t < 2560) {
        int e = t - 2048;
        int l = e & 63, nt = e >> 6;
        int col = nt * 16 + (l & 15);
        int k0 = (l >> 4) * 8;
        short8 v;
        #pragma unroll
        for (int j = 0; j < 8; ++j) v[j] = (short)f2bf(We[(k0 + j) * 128 + col]);
        Wep[e] = v;
    }
}

// ---------------------------------------------------------------------------
// One-dispatch exclusive scan: each block redundantly sums deg[0 .. b*1024)
// ---------------------------------------------------------------------------
__global__ __launch_bounds__(256) void scan_kernel(const int* __restrict__ deg,
                                                   int* __restrict__ rowp) {
    __shared__ int red[256];
    int b = blockIdx.x, tid = threadIdx.x;
    int pre = 0;
    int limit = b * 1024;
    for (int i = tid; i < limit; i += 256) pre += deg[i];
    red[tid] = pre;
    __syncthreads();
    for (int off = 128; off > 0; off >>= 1) {
        if (tid < off) red[tid] += red[tid + off];
        __syncthreads();
    }
    int base = red[0];
    __syncthreads();
    int basei = b * 1024 + tid * 4;
    int v[4];
    int s = 0;
    #pragma unroll
    for (int j = 0; j < 4; ++j) {
        int i = basei + j;
        v[j] = (i < N_NODES) ? deg[i] : 0;
        s += v[j];
    }
    red[tid] = s;
    __syncthreads();
    for (int off = 1; off < 256; off <<= 1) {
        int t = (tid >= off) ? red[tid - off] : 0;
        __syncthreads();
        red[tid] += t;
        __syncthreads();
    }
    int excl = base + red[tid] - s;
    #pragma unroll
    for (int j = 0; j < 4; ++j) {
        int i = basei + j;
        if (i < N_NODES) rowp[i] = excl;
        excl += v[j];
    }
    if (b == 0 && tid == 0) rowp[N_NODES] = N_EDGES;
}

// ---------------------------------------------------------------------------
// CSR fill, atomic-free: csr_pk[rowp[d] + rank[e]] = (eid << 32) | src
// ---------------------------------------------------------------------------
__global__ void fill_csr_kernel(const int* __restrict__ eidx,
                                const int* __restrict__ rowp,
                                const int* __restrict__ rank,
                                uint64* __restrict__ csr_pk) {
    int e = blockIdx.x * 256 + threadIdx.x;
    if (e >= N_EDGES) return;
    int d = eidx[N_EDGES + e];
    csr_pk[rowp[d] + rank[e]] = ((uint64)(uint32)e << 32) | (uint32)eidx[e];
}

// ---------------------------------------------------------------------------
// Eab[d] = bf16( sum of edge_attr rows with dst == d )   (GEMM A-operand)
// ---------------------------------------------------------------------------
__global__ __launch_bounds__(256) void ea_gather_kernel(
        const float* __restrict__ edge_attr,
        const int* __restrict__ rowp,
        const uint64* __restrict__ csr_pk,
        ushort* __restrict__ Eab) {
    int node = blockIdx.x * 8 + (threadIdx.x >> 5);
    int c = threadIdx.x & 31;
    if (node >= N_NODES) return;
    int beg = rowp[node], end = rowp[node + 1];
    float s0 = 0.f, s1 = 0.f, s2 = 0.f, s3 = 0.f;
    int p = beg;
    for (; p + 4 <= end; p += 4) {
        int e0 = (int)(csr_pk[p]     >> 32);
        int e1 = (int)(csr_pk[p + 1] >> 32);
        int e2 = (int)(csr_pk[p + 2] >> 32);
        int e3 = (int)(csr_pk[p + 3] >> 32);
        s0 += edge_attr[e0 * EDGE_DIM + c];
        s1 += edge_attr[e1 * EDGE_DIM + c];
        s2 += edge_attr[e2 * EDGE_DIM + c];
        s3 += edge_attr[e3 * EDGE_DIM + c];
    }
    for (; p < end; ++p)
        s0 += edge_attr[(int)(csr_pk[p] >> 32) * EDGE_DIM + c];
    Eab[node * EDGE_DIM + c] = f2bf((s0 + s1) + (s2 + s3));
}

// ---------------------------------------------------------------------------
// MFMA GEMM; BN scale/shift computed in-block by folding the NREP csq
// replicas (written by the previous layer's gather) — no stats dispatch.
// ---------------------------------------------------------------------------
template <bool BN>
__global__ __launch_bounds__(256) void gemm_mfma_kernel(
        const float* __restrict__ X, const short8* __restrict__ Wnp,
        const float* __restrict__ bnb,
        const ushort* __restrict__ eab, const short8* __restrict__ Wep,
        const float* __restrict__ be, const int* __restrict__ deg,
        const float* __restrict__ csq,          // [NREP][256]
        const float* __restrict__ gamma, const float* __restrict__ beta,
        ushort* __restrict__ h16, float* __restrict__ acc) {
    __shared__ __align__(16) float scs[128];
    __shared__ __align__(16) float shs[128];
    const int tid = threadIdx.x;
    if (BN) {
        if (tid < 128) {
            float ssum = 0.f, qsum = 0.f;
            #pragma unroll 4
            for (int r = 0; r < NREP; ++r) {
                ssum += csq[r * 256 + tid];
                qsum += csq[r * 256 + 128 + tid];
            }
            const float invN = 1.0f / (float)N_NODES;
            float mu = ssum * invN;
            float var = qsum * invN - mu * mu;
            float sc = gamma[tid] * rsqrtf(var + BN_EPS);
            scs[tid] = sc;
            shs[tid] = beta[tid] - mu * sc;
        }
        __syncthreads();
    }

    const int wid = tid >> 6, L = tid & 63;
    const int g = blockIdx.x * 4 + wid;
    if (g >= NGRP16) return;                    // wave-uniform exit (after barrier)
    const int r0 = g * 16;
    const int m = L & 15, kq = L >> 4;

    short8 afr[4];
    const float* xrow = X + (size_t)(r0 + m) * 128 + kq * 8;
    #pragma unroll
    for (int kb = 0; kb < 4; ++kb) {
        float v[8];
        *(float4*)&v[0] = *(const float4*)(xrow + kb * 32);
        *(float4*)&v[4] = *(const float4*)(xrow + kb * 32 + 4);
        if (BN) {
            float s[8], h[8];
            *(float4*)&s[0] = *(const float4*)(scs + kb * 32 + kq * 8);
            *(float4*)&s[4] = *(const float4*)(scs + kb * 32 + kq * 8 + 4);
            *(float4*)&h[0] = *(const float4*)(shs + kb * 32 + kq * 8);
            *(float4*)&h[4] = *(const float4*)(shs + kb * 32 + kq * 8 + 4);
            #pragma unroll
            for (int j = 0; j < 8; ++j)
                v[j] = fmaxf(0.f, v[j] * s[j] + h[j]);
        }
        short8 a;
        #pragma unroll
        for (int j = 0; j < 8; ++j) a[j] = (short)f2bf(v[j]);
        afr[kb] = a;
    }

    f32x4 d[8];
    #pragma unroll
    for (int nt = 0; nt < 8; ++nt) d[nt] = (f32x4)(0.f);

    #pragma unroll
    for (int kb = 0; kb < 4; ++kb) {
        #pragma unroll
        for (int nt = 0; nt < 8; ++nt) {
            short8 b = Wnp[(nt * 4 + kb) * 64 + L];
            d[nt] = __builtin_amdgcn_mfma_f32_16x16x32_bf16(afr[kb], b, d[nt], 0, 0, 0);
        }
    }

    float bnv[8], bev[8];
    #pragma unroll
    for (int nt = 0; nt < 8; ++nt) {
        bnv[nt] = bnb[nt * 16 + m];
        bev[nt] = be[nt * 16 + m];
    }

    #pragma unroll
    for (int nt = 0; nt < 8; ++nt) {
        #pragma unroll
        for (int i = 0; i < 4; ++i)
            h16[(size_t)(r0 + kq * 4 + i) * 128 + nt * 16 + m] =
                f2bf(d[nt][i] + bnv[nt]);
    }

    short8 ae = *(const short8*)(eab + (size_t)(r0 + m) * 32 + kq * 8);
    #pragma unroll
    for (int nt = 0; nt < 8; ++nt)
        d[nt] = __builtin_amdgcn_mfma_f32_16x16x32_bf16(ae, Wep[nt * 64 + L], d[nt], 0, 0, 0);

    float dg[4];
    #pragma unroll
    for (int i = 0; i < 4; ++i) dg[i] = (float)deg[r0 + kq * 4 + i];

    #pragma unroll
    for (int nt = 0; nt < 8; ++nt) {
        #pragma unroll
        for (int i = 0; i < 4; ++i)
            acc[(size_t)(r0 + kq * 4 + i) * 128 + nt * 16 + m] =
                d[nt][i] + bnv[nt] + dg[i] * bev[nt];
    }
}

// ---------------------------------------------------------------------------
// acc[d] += sum over CSR edges of h_bf16[src]  — fused column stats.
// ONE NODE PER WAVE (4/block, grid 12500). Block-level stats go straight
// into csq replica (blockIdx & 31) via fp32 atomics (~390 per address).
// ---------------------------------------------------------------------------
__global__ __launch_bounds__(256) void gather_kernel(
        const uint32* __restrict__ h32,      // 64 uints (=128 bf16) per row
        const int* __restrict__ rowp, const uint64* __restrict__ csr_pk,
        float* __restrict__ acc, float* __restrict__ csq) {
    __shared__ float red_s[4][128];
    __shared__ float red_q[4][128];
    int wid = threadIdx.x >> 6, lane = threadIdx.x & 63;
    int node = blockIdx.x * 4 + wid;             // < N_NODES (12500*4 exact)
    int beg = rowp[node], end = rowp[node + 1];
    float sx[8] = {0.f,0.f,0.f,0.f,0.f,0.f,0.f,0.f};
    float sy[8] = {0.f,0.f,0.f,0.f,0.f,0.f,0.f,0.f};
    int p = beg;
    for (; p + 8 <= end; p += 8) {
        uint32 v[8];
        #pragma unroll
        for (int j = 0; j < 8; ++j)
            v[j] = h32[(int)(uint32)csr_pk[p + j] * 64 + lane];
        #pragma unroll
        for (int j = 0; j < 8; ++j) {
            sx[j] += __uint_as_float(v[j] << 16);
            sy[j] += __uint_as_float(v[j] & 0xffff0000u);
        }
    }
    for (; p + 4 <= end; p += 4) {
        uint32 v[4];
        #pragma unroll
        for (int j = 0; j < 4; ++j)
            v[j] = h32[(int)(uint32)csr_pk[p + j] * 64 + lane];
        #pragma unroll
        for (int j = 0; j < 4; ++j) {
            sx[j] += __uint_as_float(v[j] << 16);
            sy[j] += __uint_as_float(v[j] & 0xffff0000u);
        }
    }
    for (; p < end; ++p) {
        uint32 v = h32[(int)(uint32)csr_pk[p] * 64 + lane];
        sx[0] += __uint_as_float(v << 16);
        sy[0] += __uint_as_float(v & 0xffff0000u);
    }
    float2* ap = (float2*)&acc[(size_t)node * 128 + lane * 2];
    float2 a = *ap;
    a.x += ((sx[0] + sx[1]) + (sx[2] + sx[3])) + ((sx[4] + sx[5]) + (sx[6] + sx[7]));
    a.y += ((sy[0] + sy[1]) + (sy[2] + sy[3])) + ((sy[4] + sy[5]) + (sy[6] + sy[7]));
    *ap = a;
    red_s[wid][lane * 2]     = a.x;
    red_s[wid][lane * 2 + 1] = a.y;
    red_q[wid][lane * 2]     = a.x * a.x;
    red_q[wid][lane * 2 + 1] = a.y * a.y;
    __syncthreads();
    int t = threadIdx.x;
    float* rep = csq + (size_t)(blockIdx.x & (NREP - 1)) * 256;
    if (t < 128) {
        float s = (red_s[0][t] + red_s[1][t]) + (red_s[2][t] + red_s[3][t]);
        unsafeAtomicAdd(&rep[t], s);
    } else {
        int c = t - 128;
        float q = (red_q[0][c] + red_q[1][c]) + (red_q[2][c] + red_q[3][c]);
        unsafeAtomicAdd(&rep[128 + c], q);
    }
}

// ---------------------------------------------------------------------------
// One block per graph (batch is sorted): fold csq replicas for layer-3 BN,
// mean-pool, 128->2 FC. No atomics.
// ---------------------------------------------------------------------------
__global__ __launch_bounds__(256) void pool_fc_kernel(
        const float* __restrict__ acc,
        const float* __restrict__ csq,          // [NREP][256]
        const float* __restrict__ gamma, const float* __restrict__ beta,
        const int* __restrict__ batch,
        const float* __restrict__ Wfc, const float* __restrict__ bfc,
        float* __restrict__ out) {
    __shared__ float ps[256];
    int g = blockIdx.x;
    int lo = 0, hi = N_NODES;
    while (lo < hi) { int mid = (lo + hi) >> 1; if (batch[mid] < g) lo = mid + 1; else hi = mid; }
    int start = lo;
    hi = N_NODES;
    while (lo < hi) { int mid = (lo + hi) >> 1; if (batch[mid] < g + 1) lo = mid + 1; else hi = mid; }
    int end = lo;

    int c = threadIdx.x & 127;
    int half = threadIdx.x >> 7;
    float ssum = 0.f, qsum = 0.f;
    #pragma unroll 4
    for (int r = 0; r < NREP; ++r) {
        ssum += csq[r * 256 + c];
        qsum += csq[r * 256 + 128 + c];
    }
    const float invN = 1.0f / (float)N_NODES;
    float mu = ssum * invN;
    float var = qsum * invN - mu * mu;
    float sc = gamma[c] * rsqrtf(var + BN_EPS);
    float sh = beta[c] - mu * sc;
    float s = 0.f;
    for (int r = start + half; r < end; r += 2)
        s += fmaxf(0.f, acc[r * 128 + c] * sc + sh);
    ps[threadIdx.x] = s;
    __syncthreads();
    if (half == 0)
        ps[c] = (ps[c] + ps[c + 128]) / fmaxf((float)(end - start), 1.0f);
    __syncthreads();
    if (threadIdx.x < 2) {
        int o = threadIdx.x;
        float t = 0.f;
        #pragma unroll 16
        for (int cc = 0; cc < 128; ++cc) t += ps[cc] * Wfc[cc * 2 + o];
        out[g * 2 + o] = t + bfc[o];
    }
}

// ---------------------------------------------------------------------------
extern "C" void kernel_launch(void* const* d_in, const int* in_sizes, int n_in,
                              void* d_out, int out_size, void* d_ws, size_t ws_size,
                              hipStream_t stream) {
    const float* x         = (const float*)d_in[0];
    const float* edge_attr = (const float*)d_in[1];
    const int*   eidx      = (const int*)d_in[2];
    const int*   batch     = (const int*)d_in[3];
    const float* Wn[3]  = {(const float*)d_in[4],  (const float*)d_in[8],  (const float*)d_in[12]};
    const float* bnb[3] = {(const float*)d_in[5],  (const float*)d_in[9],  (const float*)d_in[13]};
    const float* We[3]  = {(const float*)d_in[6],  (const float*)d_in[10], (const float*)d_in[14]};
    const float* be[3]  = {(const float*)d_in[7],  (const float*)d_in[11], (const float*)d_in[15]};
    const float* gm[3]  = {(const float*)d_in[16], (const float*)d_in[18], (const float*)d_in[20]};
    const float* bt[3]  = {(const float*)d_in[17], (const float*)d_in[19], (const float*)d_in[21]};
    const float* Wfc = (const float*)d_in[22];
    const float* bfc = (const float*)d_in[23];
    float* out = (float*)d_out;

    char* p = (char*)d_ws;
    auto alloc = [&](size_t bytes) {
        char* q = p;
        p += (bytes + 255) & ~size_t(255);
        return q;
    };
    // --- zero-region: deg + csq replicas contiguous (single memset) ---
    int*    deg    = (int*)alloc(sizeof(int) * N_NODES);
    float*  csq    = (float*)alloc(sizeof(float) * 3 * NREP * 256);  // per-layer replicas
    size_t  zbytes = (size_t)((char*)csq + sizeof(float) * 3 * NREP * 256 - (char*)deg);
    // --- rest ---
    int*    rank   = (int*)alloc(sizeof(int) * N_EDGES);
    ushort* h16    = (ushort*)alloc(sizeof(ushort) * N_NODES * HID);      // bf16 h
    ushort* Eab    = (ushort*)alloc(sizeof(ushort) * N_NODES * EDGE_DIM); // bf16 Ea
    float*  accA   = (float*)alloc(sizeof(float) * N_NODES * HID);
    float*  accB   = (float*)alloc(sizeof(float) * N_NODES * HID);
    int*    rowp   = (int*)alloc(sizeof(int) * (N_NODES + 1));
    uint64* csr_pk = (uint64*)alloc(sizeof(uint64) * N_EDGES);
    short8* Wnp[3]; short8* Wep[3];
    for (int l = 0; l < 3; ++l) {
        Wnp[l] = (short8*)alloc(sizeof(short8) * 2048);
        Wep[l] = (short8*)alloc(sizeof(short8) * 512);
    }

    hipMemsetAsync(deg, 0, zbytes, stream);

    pre_kernel<<<2530, 256, 0, stream>>>(eidx, deg, rank,
        Wn[0], We[0], Wn[1], We[1], Wn[2], We[2],
        Wnp[0], Wep[0], Wnp[1], Wep[1], Wnp[2], Wep[2]);
    scan_kernel<<<NSCB, 256, 0, stream>>>(deg, rowp);
    fill_csr_kernel<<<(N_EDGES + 255) / 256, 256, 0, stream>>>(eidx, rowp, rank, csr_pk);
    ea_gather_kernel<<<(N_NODES + 7) / 8, 256, 0, stream>>>(edge_attr, rowp, csr_pk, Eab);

    float* accs[3] = {accA, accB, accA};
    for (int l = 0; l < 3; ++l) {
        float* acc = accs[l];
        const float* Xin = (l == 0) ? x : accs[l - 1];
        if (l == 0) {
            gemm_mfma_kernel<false><<<(NGRP16 + 3) / 4, 256, 0, stream>>>(
                Xin, Wnp[l], bnb[l], Eab, Wep[l], be[l], deg,
                nullptr, nullptr, nullptr, h16, acc);
        } else {
            gemm_mfma_kernel<true><<<(NGRP16 + 3) / 4, 256, 0, stream>>>(
                Xin, Wnp[l], bnb[l], Eab, Wep[l], be[l], deg,
                csq + (size_t)(l - 1) * NREP * 256, gm[l - 1], bt[l - 1], h16, acc);
        }
        gather_kernel<<<NGB4, 256, 0, stream>>>(
            (const uint32*)h16, rowp, csr_pk, acc, csq + (size_t)l * NREP * 256);
    }
    pool_fc_kernel<<<NUM_GRAPHS, 256, 0, stream>>>(
        accs[2], csq + (size_t)2 * NREP * 256, gm[2], bt[2], batch, Wfc, bfc, out);
}

// Round 19
// 295.946 us; speedup vs baseline: 2.3046x; 1.0039x over previous
//
#include <hip/hip_runtime.h>

#define N_NODES 50000
#define N_EDGES 640000
#define HID 128
#define EDGE_DIM 32
#define NUM_GRAPHS 512
#define BN_EPS 1e-5f
#define NGRP16 3125    // N_NODES / 16 (exact)
#define NGB4 12500     // N_NODES / 4 (exact) — gather blocks
#define NSCB 49        // ceil(N_NODES/1024)
#define NREP 32        // csq replicas (bounds per-address atomic depth)

typedef unsigned int uint32;
typedef unsigned long long uint64;
typedef unsigned short ushort;
typedef __attribute__((ext_vector_type(8))) short short8;   // 8 bf16 (4 VGPR)
typedef __attribute__((ext_vector_type(4))) float f32x4;    // MFMA accum

// round-to-nearest-even f32 -> bf16 bits
__device__ inline ushort f2bf(float x) {
    uint32 u = __float_as_uint(x);
    return (ushort)((u + 0x7fff + ((u >> 16) & 1)) >> 16);
}

// ---------------------------------------------------------------------------
// Merged preprocessing: blocks [0,2500) histogram deg AND record each edge's
// rank within its dst bucket; blocks [2500,2530) pack the 3 layers' weights.
// ---------------------------------------------------------------------------
__global__ __launch_bounds__(256) void pre_kernel(
        const int* __restrict__ eidx, int* __restrict__ deg,
        int* __restrict__ rank,
        const float* __restrict__ Wn0, const float* __restrict__ We0,
        const float* __restrict__ Wn1, const float* __restrict__ We1,
        const float* __restrict__ Wn2, const float* __restrict__ We2,
        short8* __restrict__ Wnp0, short8* __restrict__ Wep0,
        short8* __restrict__ Wnp1, short8* __restrict__ Wep1,
        short8* __restrict__ Wnp2, short8* __restrict__ Wep2) {
    int b = blockIdx.x;
    if (b < 2500) {
        int e = b * 256 + threadIdx.x;          // N_EDGES = 2500*256 exactly
        int d = eidx[N_EDGES + e];
        rank[e] = atomicAdd(&deg[d], 1);
        return;
    }
    int idx = b - 2500;                          // 0..29
    int layer = idx / 10;
    int t = (idx % 10) * 256 + threadIdx.x;      // 0..2559
    const float* Wn = (layer == 0) ? Wn0 : (layer == 1) ? Wn1 : Wn2;
    const float* We = (layer == 0) ? We0 : (layer == 1) ? We1 : We2;
    short8* Wnp = (layer == 0) ? Wnp0 : (layer == 1) ? Wnp1 : Wnp2;
    short8* Wep = (layer == 0) ? Wep0 : (layer == 1) ? Wep1 : Wep2;
    if (t < 2048) {
        int l = t & 63, rest = t >> 6;
        int kb = rest & 3, nt = rest >> 2;
        int col = nt * 16 + (l & 15);
        int k0 = kb * 32 + (l >> 4) * 8;
        short8 v;
        #pragma unroll
        for (int j = 0; j < 8; ++j) v[j] = (short)f2bf(Wn[(k0 + j) * 128 + col]);
        Wnp[t] = v;
    } else if (t < 2560) {
        int e = t - 2048;
        int l = e & 63, nt = e >> 6;
        int col = nt * 16 + (l & 15);
        int k0 = (l >> 4) * 8;
        short8 v;
        #pragma unroll
        for (int j = 0; j < 8; ++j) v[j] = (short)f2bf(We[(k0 + j) * 128 + col]);
        Wep[e] = v;
    }
}

// ---------------------------------------------------------------------------
// One-dispatch exclusive scan: each block redundantly sums deg[0 .. b*1024)
// ---------------------------------------------------------------------------
__global__ __launch_bounds__(256) void scan_kernel(const int* __restrict__ deg,
                                                   int* __restrict__ rowp) {
    __shared__ int red[256];
    int b = blockIdx.x, tid = threadIdx.x;
    int pre = 0;
    int limit = b * 1024;
    for (int i = tid; i < limit; i += 256) pre += deg[i];
    red[tid] = pre;
    __syncthreads();
    for (int off = 128; off > 0; off >>= 1) {
        if (tid < off) red[tid] += red[tid + off];
        __syncthreads();
    }
    int base = red[0];
    __syncthreads();
    int basei = b * 1024 + tid * 4;
    int v[4];
    int s = 0;
    #pragma unroll
    for (int j = 0; j < 4; ++j) {
        int i = basei + j;
        v[j] = (i < N_NODES) ? deg[i] : 0;
        s += v[j];
    }
    red[tid] = s;
    __syncthreads();
    for (int off = 1; off < 256; off <<= 1) {
        int t = (tid >= off) ? red[tid - off] : 0;
        __syncthreads();
        red[tid] += t;
        __syncthreads();
    }
    int excl = base + red[tid] - s;
    #pragma unroll
    for (int j = 0; j < 4; ++j) {
        int i = basei + j;
        if (i < N_NODES) rowp[i] = excl;
        excl += v[j];
    }
    if (b == 0 && tid == 0) rowp[N_NODES] = N_EDGES;
}

// ---------------------------------------------------------------------------
// CSR fill, atomic-free: csr_pk[rowp[d] + rank[e]] = (eid << 32) | src
// ---------------------------------------------------------------------------
__global__ void fill_csr_kernel(const int* __restrict__ eidx,
                                const int* __restrict__ rowp,
                                const int* __restrict__ rank,
                                uint64* __restrict__ csr_pk) {
    int e = blockIdx.x * 256 + threadIdx.x;
    if (e >= N_EDGES) return;
    int d = eidx[N_EDGES + e];
    csr_pk[rowp[d] + rank[e]] = ((uint64)(uint32)e << 32) | (uint32)eidx[e];
}

// ---------------------------------------------------------------------------
// MFMA GEMM. Layer 0 (EAG=true): each lane CSR-gathers its own node's 8
// edge_attr columns — the lane->(node,col) map IS the edge-GEMM A-frag
// layout (m = L&15, cols kq*8..+8) — uses the fp32 sums directly and
// stores bf16 Eab for layers 1-2. Layers 1-2 (BN=true): load Eab, fold
// NREP csq replicas for BN scale/shift in-block.
// ---------------------------------------------------------------------------
template <bool BN, bool EAG>
__global__ __launch_bounds__(256) void gemm_mfma_kernel(
        const float* __restrict__ X, const short8* __restrict__ Wnp,
        const float* __restrict__ bnb,
        ushort* __restrict__ eab, const short8* __restrict__ Wep,
        const float* __restrict__ be, const int* __restrict__ deg,
        const int* __restrict__ rowp, const uint64* __restrict__ csr_pk,
        const float* __restrict__ edge_attr,
        const float* __restrict__ csq,          // [NREP][256]
        const float* __restrict__ gamma, const float* __restrict__ beta,
        ushort* __restrict__ h16, float* __restrict__ acc) {
    __shared__ __align__(16) float scs[128];
    __shared__ __align__(16) float shs[128];
    const int tid = threadIdx.x;
    if (BN) {
        if (tid < 128) {
            float ssum = 0.f, qsum = 0.f;
            #pragma unroll 4
            for (int r = 0; r < NREP; ++r) {
                ssum += csq[r * 256 + tid];
                qsum += csq[r * 256 + 128 + tid];
            }
            const float invN = 1.0f / (float)N_NODES;
            float mu = ssum * invN;
            float var = qsum * invN - mu * mu;
            float sc = gamma[tid] * rsqrtf(var + BN_EPS);
            scs[tid] = sc;
            shs[tid] = beta[tid] - mu * sc;
        }
        __syncthreads();
    }

    const int wid = tid >> 6, L = tid & 63;
    const int g = blockIdx.x * 4 + wid;
    if (g >= NGRP16) return;                    // wave-uniform exit (after barrier)
    const int r0 = g * 16;
    const int m = L & 15, kq = L >> 4;

    // ---- edge-A fragment ----
    short8 ae;
    if (EAG) {
        // lane gathers cols kq*8..+8 of node r0+m's edge_attr sum (4-deep MLP)
        int node = r0 + m;
        int beg = rowp[node], end = rowp[node + 1];
        float4 alo[4], ahi[4];
        #pragma unroll
        for (int j = 0; j < 4; ++j) {
            alo[j] = make_float4(0.f, 0.f, 0.f, 0.f);
            ahi[j] = make_float4(0.f, 0.f, 0.f, 0.f);
        }
        int p = beg;
        for (; p + 4 <= end; p += 4) {
            int e0 = (int)(csr_pk[p]     >> 32);
            int e1 = (int)(csr_pk[p + 1] >> 32);
            int e2 = (int)(csr_pk[p + 2] >> 32);
            int e3 = (int)(csr_pk[p + 3] >> 32);
            const float* q0 = edge_attr + (size_t)e0 * 32 + kq * 8;
            const float* q1 = edge_attr + (size_t)e1 * 32 + kq * 8;
            const float* q2 = edge_attr + (size_t)e2 * 32 + kq * 8;
            const float* q3 = edge_attr + (size_t)e3 * 32 + kq * 8;
            float4 l0 = *(const float4*)q0, h0 = *(const float4*)(q0 + 4);
            float4 l1 = *(const float4*)q1, h1 = *(const float4*)(q1 + 4);
            float4 l2 = *(const float4*)q2, h2 = *(const float4*)(q2 + 4);
            float4 l3 = *(const float4*)q3, h3 = *(const float4*)(q3 + 4);
            alo[0].x += l0.x; alo[0].y += l0.y; alo[0].z += l0.z; alo[0].w += l0.w;
            ahi[0].x += h0.x; ahi[0].y += h0.y; ahi[0].z += h0.z; ahi[0].w += h0.w;
            alo[1].x += l1.x; alo[1].y += l1.y; alo[1].z += l1.z; alo[1].w += l1.w;
            ahi[1].x += h1.x; ahi[1].y += h1.y; ahi[1].z += h1.z; ahi[1].w += h1.w;
            alo[2].x += l2.x; alo[2].y += l2.y; alo[2].z += l2.z; alo[2].w += l2.w;
            ahi[2].x += h2.x; ahi[2].y += h2.y; ahi[2].z += h2.z; ahi[2].w += h2.w;
            alo[3].x += l3.x; alo[3].y += l3.y; alo[3].z += l3.z; alo[3].w += l3.w;
            ahi[3].x += h3.x; ahi[3].y += h3.y; ahi[3].z += h3.z; ahi[3].w += h3.w;
        }
        for (; p < end; ++p) {
            int e0 = (int)(csr_pk[p] >> 32);
            const float* q0 = edge_attr + (size_t)e0 * 32 + kq * 8;
            float4 l0 = *(const float4*)q0, h0 = *(const float4*)(q0 + 4);
            alo[0].x += l0.x; alo[0].y += l0.y; alo[0].z += l0.z; alo[0].w += l0.w;
            ahi[0].x += h0.x; ahi[0].y += h0.y; ahi[0].z += h0.z; ahi[0].w += h0.w;
        }
        float es[8];
        es[0] = (alo[0].x + alo[1].x) + (alo[2].x + alo[3].x);
        es[1] = (alo[0].y + alo[1].y) + (alo[2].y + alo[3].y);
        es[2] = (alo[0].z + alo[1].z) + (alo[2].z + alo[3].z);
        es[3] = (alo[0].w + alo[1].w) + (alo[2].w + alo[3].w);
        es[4] = (ahi[0].x + ahi[1].x) + (ahi[2].x + ahi[3].x);
        es[5] = (ahi[0].y + ahi[1].y) + (ahi[2].y + ahi[3].y);
        es[6] = (ahi[0].z + ahi[1].z) + (ahi[2].z + ahi[3].z);
        es[7] = (ahi[0].w + ahi[1].w) + (ahi[2].w + ahi[3].w);
        #pragma unroll
        for (int j = 0; j < 8; ++j) ae[j] = (short)f2bf(es[j]);
        *(short8*)(eab + (size_t)node * 32 + kq * 8) = ae;   // for layers 1-2
    } else {
        ae = *(const short8*)(eab + (size_t)(r0 + m) * 32 + kq * 8);
    }

    // ---- node-A fragments (BN+ReLU inline, cast bf16) ----
    short8 afr[4];
    const float* xrow = X + (size_t)(r0 + m) * 128 + kq * 8;
    #pragma unroll
    for (int kb = 0; kb < 4; ++kb) {
        float v[8];
        *(float4*)&v[0] = *(const float4*)(xrow + kb * 32);
        *(float4*)&v[4] = *(const float4*)(xrow + kb * 32 + 4);
        if (BN) {
            float s[8], h[8];
            *(float4*)&s[0] = *(const float4*)(scs + kb * 32 + kq * 8);
            *(float4*)&s[4] = *(const float4*)(scs + kb * 32 + kq * 8 + 4);
            *(float4*)&h[0] = *(const float4*)(shs + kb * 32 + kq * 8);
            *(float4*)&h[4] = *(const float4*)(shs + kb * 32 + kq * 8 + 4);
            #pragma unroll
            for (int j = 0; j < 8; ++j)
                v[j] = fmaxf(0.f, v[j] * s[j] + h[j]);
        }
        short8 a;
        #pragma unroll
        for (int j = 0; j < 8; ++j) a[j] = (short)f2bf(v[j]);
        afr[kb] = a;
    }

    f32x4 d[8];
    #pragma unroll
    for (int nt = 0; nt < 8; ++nt) d[nt] = (f32x4)(0.f);

    // node GEMM: K = 128
    #pragma unroll
    for (int kb = 0; kb < 4; ++kb) {
        #pragma unroll
        for (int nt = 0; nt < 8; ++nt) {
            short8 b = Wnp[(nt * 4 + kb) * 64 + L];
            d[nt] = __builtin_amdgcn_mfma_f32_16x16x32_bf16(afr[kb], b, d[nt], 0, 0, 0);
        }
    }

    float bnv[8], bev[8];
    #pragma unroll
    for (int nt = 0; nt < 8; ++nt) {
        bnv[nt] = bnb[nt * 16 + m];
        bev[nt] = be[nt * 16 + m];
    }

    #pragma unroll
    for (int nt = 0; nt < 8; ++nt) {
        #pragma unroll
        for (int i = 0; i < 4; ++i)
            h16[(size_t)(r0 + kq * 4 + i) * 128 + nt * 16 + m] =
                f2bf(d[nt][i] + bnv[nt]);
    }

    // edge GEMM: K = 32 (one step)
    #pragma unroll
    for (int nt = 0; nt < 8; ++nt)
        d[nt] = __builtin_amdgcn_mfma_f32_16x16x32_bf16(ae, Wep[nt * 64 + L], d[nt], 0, 0, 0);

    float dg[4];
    #pragma unroll
    for (int i = 0; i < 4; ++i) dg[i] = (float)deg[r0 + kq * 4 + i];

    #pragma unroll
    for (int nt = 0; nt < 8; ++nt) {
        #pragma unroll
        for (int i = 0; i < 4; ++i)
            acc[(size_t)(r0 + kq * 4 + i) * 128 + nt * 16 + m] =
                d[nt][i] + bnv[nt] + dg[i] * bev[nt];
    }
}

// ---------------------------------------------------------------------------
// acc[d] += sum over CSR edges of h_bf16[src]  — fused column stats.
// ONE NODE PER WAVE (4/block, grid 12500). Block-level stats go straight
// into csq replica (blockIdx & 31) via fp32 atomics.
// ---------------------------------------------------------------------------
__global__ __launch_bounds__(256) void gather_kernel(
        const uint32* __restrict__ h32,      // 64 uints (=128 bf16) per row
        const int* __restrict__ rowp, const uint64* __restrict__ csr_pk,
        float* __restrict__ acc, float* __restrict__ csq) {
    __shared__ float red_s[4][128];
    __shared__ float red_q[4][128];
    int wid = threadIdx.x >> 6, lane = threadIdx.x & 63;
    int node = blockIdx.x * 4 + wid;             // < N_NODES (12500*4 exact)
    int beg = rowp[node], end = rowp[node + 1];
    float sx[8] = {0.f,0.f,0.f,0.f,0.f,0.f,0.f,0.f};
    float sy[8] = {0.f,0.f,0.f,0.f,0.f,0.f,0.f,0.f};
    int p = beg;
    for (; p + 8 <= end; p += 8) {
        uint32 v[8];
        #pragma unroll
        for (int j = 0; j < 8; ++j)
            v[j] = h32[(int)(uint32)csr_pk[p + j] * 64 + lane];
        #pragma unroll
        for (int j = 0; j < 8; ++j) {
            sx[j] += __uint_as_float(v[j] << 16);
            sy[j] += __uint_as_float(v[j] & 0xffff0000u);
        }
    }
    for (; p + 4 <= end; p += 4) {
        uint32 v[4];
        #pragma unroll
        for (int j = 0; j < 4; ++j)
            v[j] = h32[(int)(uint32)csr_pk[p + j] * 64 + lane];
        #pragma unroll
        for (int j = 0; j < 4; ++j) {
            sx[j] += __uint_as_float(v[j] << 16);
            sy[j] += __uint_as_float(v[j] & 0xffff0000u);
        }
    }
    for (; p < end; ++p) {
        uint32 v = h32[(int)(uint32)csr_pk[p] * 64 + lane];
        sx[0] += __uint_as_float(v << 16);
        sy[0] += __uint_as_float(v & 0xffff0000u);
    }
    float2* ap = (float2*)&acc[(size_t)node * 128 + lane * 2];
    float2 a = *ap;
    a.x += ((sx[0] + sx[1]) + (sx[2] + sx[3])) + ((sx[4] + sx[5]) + (sx[6] + sx[7]));
    a.y += ((sy[0] + sy[1]) + (sy[2] + sy[3])) + ((sy[4] + sy[5]) + (sy[6] + sy[7]));
    *ap = a;
    red_s[wid][lane * 2]     = a.x;
    red_s[wid][lane * 2 + 1] = a.y;
    red_q[wid][lane * 2]     = a.x * a.x;
    red_q[wid][lane * 2 + 1] = a.y * a.y;
    __syncthreads();
    int t = threadIdx.x;
    float* rep = csq + (size_t)(blockIdx.x & (NREP - 1)) * 256;
    if (t < 128) {
        float s = (red_s[0][t] + red_s[1][t]) + (red_s[2][t] + red_s[3][t]);
        unsafeAtomicAdd(&rep[t], s);
    } else {
        int c = t - 128;
        float q = (red_q[0][c] + red_q[1][c]) + (red_q[2][c] + red_q[3][c]);
        unsafeAtomicAdd(&rep[128 + c], q);
    }
}

// ---------------------------------------------------------------------------
// One block per graph (batch is sorted): fold csq replicas for layer-3 BN,
// mean-pool, 128->2 FC. No atomics.
// ---------------------------------------------------------------------------
__global__ __launch_bounds__(256) void pool_fc_kernel(
        const float* __restrict__ acc,
        const float* __restrict__ csq,          // [NREP][256]
        const float* __restrict__ gamma, const float* __restrict__ beta,
        const int* __restrict__ batch,
        const float* __restrict__ Wfc, const float* __restrict__ bfc,
        float* __restrict__ out) {
    __shared__ float ps[256];
    int g = blockIdx.x;
    int lo = 0, hi = N_NODES;
    while (lo < hi) { int mid = (lo + hi) >> 1; if (batch[mid] < g) lo = mid + 1; else hi = mid; }
    int start = lo;
    hi = N_NODES;
    while (lo < hi) { int mid = (lo + hi) >> 1; if (batch[mid] < g + 1) lo = mid + 1; else hi = mid; }
    int end = lo;

    int c = threadIdx.x & 127;
    int half = threadIdx.x >> 7;
    float ssum = 0.f, qsum = 0.f;
    #pragma unroll 4
    for (int r = 0; r < NREP; ++r) {
        ssum += csq[r * 256 + c];
        qsum += csq[r * 256 + 128 + c];
    }
    const float invN = 1.0f / (float)N_NODES;
    float mu = ssum * invN;
    float var = qsum * invN - mu * mu;
    float sc = gamma[c] * rsqrtf(var + BN_EPS);
    float sh = beta[c] - mu * sc;
    float s = 0.f;
    for (int r = start + half; r < end; r += 2)
        s += fmaxf(0.f, acc[r * 128 + c] * sc + sh);
    ps[threadIdx.x] = s;
    __syncthreads();
    if (half == 0)
        ps[c] = (ps[c] + ps[c + 128]) / fmaxf((float)(end - start), 1.0f);
    __syncthreads();
    if (threadIdx.x < 2) {
        int o = threadIdx.x;
        float t = 0.f;
        #pragma unroll 16
        for (int cc = 0; cc < 128; ++cc) t += ps[cc] * Wfc[cc * 2 + o];
        out[g * 2 + o] = t + bfc[o];
    }
}

// ---------------------------------------------------------------------------
extern "C" void kernel_launch(void* const* d_in, const int* in_sizes, int n_in,
                              void* d_out, int out_size, void* d_ws, size_t ws_size,
                              hipStream_t stream) {
    const float* x         = (const float*)d_in[0];
    const float* edge_attr = (const float*)d_in[1];
    const int*   eidx      = (const int*)d_in[2];
    const int*   batch     = (const int*)d_in[3];
    const float* Wn[3]  = {(const float*)d_in[4],  (const float*)d_in[8],  (const float*)d_in[12]};
    const float* bnb[3] = {(const float*)d_in[5],  (const float*)d_in[9],  (const float*)d_in[13]};
    const float* We[3]  = {(const float*)d_in[6],  (const float*)d_in[10], (const float*)d_in[14]};
    const float* be[3]  = {(const float*)d_in[7],  (const float*)d_in[11], (const float*)d_in[15]};
    const float* gm[3]  = {(const float*)d_in[16], (const float*)d_in[18], (const float*)d_in[20]};
    const float* bt[3]  = {(const float*)d_in[17], (const float*)d_in[19], (const float*)d_in[21]};
    const float* Wfc = (const float*)d_in[22];
    const float* bfc = (const float*)d_in[23];
    float* out = (float*)d_out;

    char* p = (char*)d_ws;
    auto alloc = [&](size_t bytes) {
        char* q = p;
        p += (bytes + 255) & ~size_t(255);
        return q;
    };
    // --- zero-region: deg + csq replicas contiguous (single memset) ---
    int*    deg    = (int*)alloc(sizeof(int) * N_NODES);
    float*  csq    = (float*)alloc(sizeof(float) * 3 * NREP * 256);  // per-layer replicas
    size_t  zbytes = (size_t)((char*)csq + sizeof(float) * 3 * NREP * 256 - (char*)deg);
    // --- rest ---
    int*    rank   = (int*)alloc(sizeof(int) * N_EDGES);
    ushort* h16    = (ushort*)alloc(sizeof(ushort) * N_NODES * HID);      // bf16 h
    ushort* Eab    = (ushort*)alloc(sizeof(ushort) * N_NODES * EDGE_DIM); // bf16 Ea
    float*  accA   = (float*)alloc(sizeof(float) * N_NODES * HID);
    float*  accB   = (float*)alloc(sizeof(float) * N_NODES * HID);
    int*    rowp   = (int*)alloc(sizeof(int) * (N_NODES + 1));
    uint64* csr_pk = (uint64*)alloc(sizeof(uint64) * N_EDGES);
    short8* Wnp[3]; short8* Wep[3];
    for (int l = 0; l < 3; ++l) {
        Wnp[l] = (short8*)alloc(sizeof(short8) * 2048);
        Wep[l] = (short8*)alloc(sizeof(short8) * 512);
    }

    hipMemsetAsync(deg, 0, zbytes, stream);

    pre_kernel<<<2530, 256, 0, stream>>>(eidx, deg, rank,
        Wn[0], We[0], Wn[1], We[1], Wn[2], We[2],
        Wnp[0], Wep[0], Wnp[1], Wep[1], Wnp[2], Wep[2]);
    scan_kernel<<<NSCB, 256, 0, stream>>>(deg, rowp);
    fill_csr_kernel<<<(N_EDGES + 255) / 256, 256, 0, stream>>>(eidx, rowp, rank, csr_pk);

    float* accs[3] = {accA, accB, accA};
    for (int l = 0; l < 3; ++l) {
        float* acc = accs[l];
        const float* Xin = (l == 0) ? x : accs[l - 1];
        if (l == 0) {
            gemm_mfma_kernel<false, true><<<(NGRP16 + 3) / 4, 256, 0, stream>>>(
                Xin, Wnp[l], bnb[l], Eab, Wep[l], be[l], deg,
                rowp, csr_pk, edge_attr,
                nullptr, nullptr, nullptr, h16, acc);
        } else {
            gemm_mfma_kernel<true, false><<<(NGRP16 + 3) / 4, 256, 0, stream>>>(
                Xin, Wnp[l], bnb[l], Eab, Wep[l], be[l], deg,
                rowp, csr_pk, edge_attr,
                csq + (size_t)(l - 1) * NREP * 256, gm[l - 1], bt[l - 1], h16, acc);
        }
        gather_kernel<<<NGB4, 256, 0, stream>>>(
            (const uint32*)h16, rowp, csr_pk, acc, csq + (size_t)l * NREP * 256);
    }
    pool_fc_kernel<<<NUM_GRAPHS, 256, 0, stream>>>(
        accs[2], csq + (size_t)2 * NREP * 256, gm[2], bt[2], batch, Wfc, bfc, out);
}